// Round 3
// baseline (397.120 us; speedup 1.0000x reference)
//
#include <hip/hip_runtime.h>
#include <hip/hip_bf16.h>

#define D 64
#define SCAN_B 1024

// ================= register-tiled fp32 GEMM: out = act(in[nrows x 64] @ W + bias) =================

__global__ __launch_bounds__(256) void gemm64_kernel(
    const float* __restrict__ in, int nrows,
    const float* __restrict__ W1, const float* __restrict__ W2,
    const float* __restrict__ bias, int do_relu,
    float* __restrict__ out1, float* __restrict__ out2)
{
    __shared__ float At[64][68];
    __shared__ float Ws1[64][64];
    __shared__ float Ws2[64][64];
    int tid = threadIdx.x;
    {
        const float4* w1v = (const float4*)W1;
        float4* s1 = (float4*)&Ws1[0][0];
        for (int i = tid; i < 1024; i += 256) s1[i] = w1v[i];
        if (W2) {
            const float4* w2v = (const float4*)W2;
            float4* s2 = (float4*)&Ws2[0][0];
            for (int i = tid; i < 1024; i += 256) s2[i] = w2v[i];
        }
    }
    int r0 = blockIdx.x * 64;
    for (int i = tid; i < 1024; i += 256) {
        int r = i >> 4, c4 = i & 15;
        int gr = r0 + r; if (gr >= nrows) gr = nrows - 1;
        float4 v = ((const float4*)(in + (size_t)gr * D))[c4];
        float* dp = &At[r][c4 * 4];
        dp[0] = v.x; dp[1] = v.y; dp[2] = v.z; dp[3] = v.w;
    }
    __syncthreads();

    int cg = tid & 15;
    int rg = tid >> 4;
    float acc1[4][4] = {{0.f}}, acc2[4][4] = {{0.f}};

    for (int k0 = 0; k0 < 64; k0 += 4) {
        float4 a[4], w1[4];
#pragma unroll
        for (int i = 0; i < 4; ++i) a[i] = *(const float4*)&At[4 * rg + i][k0];
#pragma unroll
        for (int j = 0; j < 4; ++j) w1[j] = *(const float4*)&Ws1[k0 + j][cg * 4];
#pragma unroll
        for (int i = 0; i < 4; ++i) {
            float av[4] = {a[i].x, a[i].y, a[i].z, a[i].w};
#pragma unroll
            for (int kk = 0; kk < 4; ++kk) {
                acc1[i][0] += av[kk] * w1[kk].x;
                acc1[i][1] += av[kk] * w1[kk].y;
                acc1[i][2] += av[kk] * w1[kk].z;
                acc1[i][3] += av[kk] * w1[kk].w;
            }
        }
        if (W2) {
            float4 w2[4];
#pragma unroll
            for (int j = 0; j < 4; ++j) w2[j] = *(const float4*)&Ws2[k0 + j][cg * 4];
#pragma unroll
            for (int i = 0; i < 4; ++i) {
                float av[4] = {a[i].x, a[i].y, a[i].z, a[i].w};
#pragma unroll
                for (int kk = 0; kk < 4; ++kk) {
                    acc2[i][0] += av[kk] * w2[kk].x;
                    acc2[i][1] += av[kk] * w2[kk].y;
                    acc2[i][2] += av[kk] * w2[kk].z;
                    acc2[i][3] += av[kk] * w2[kk].w;
                }
            }
        }
    }

    float4 bv = make_float4(0.f, 0.f, 0.f, 0.f);
    if (bias) bv = ((const float4*)bias)[cg];
#pragma unroll
    for (int i = 0; i < 4; ++i) {
        int gr = r0 + 4 * rg + i;
        if (gr < nrows) {
            float4 o;
            o.x = acc1[i][0] + bv.x; o.y = acc1[i][1] + bv.y;
            o.z = acc1[i][2] + bv.z; o.w = acc1[i][3] + bv.w;
            if (do_relu) {
                o.x = fmaxf(o.x, 0.f); o.y = fmaxf(o.y, 0.f);
                o.z = fmaxf(o.z, 0.f); o.w = fmaxf(o.w, 0.f);
            }
            ((float4*)(out1 + (size_t)gr * D))[cg] = o;
            if (out2) {
                float4 o2;
                o2.x = acc2[i][0]; o2.y = acc2[i][1]; o2.z = acc2[i][2]; o2.w = acc2[i][3];
                ((float4*)(out2 + (size_t)gr * D))[cg] = o2;
            }
        }
    }
}

// ================= CSR build =================

__global__ void deg_kernel(const int* __restrict__ dst, int* __restrict__ deg, int E) {
    int e = blockIdx.x * blockDim.x + threadIdx.x;
    if (e < E) atomicAdd(&deg[dst[e]], 1);
}

__global__ void scan1_kernel(const int* __restrict__ deg, int* __restrict__ rowptr,
                             int* __restrict__ bsum, int N) {
    __shared__ int lds[SCAN_B];
    int i = blockIdx.x * SCAN_B + threadIdx.x;
    int v = (i < N) ? deg[i] : 0;
    lds[threadIdx.x] = v;
    __syncthreads();
    for (int off = 1; off < SCAN_B; off <<= 1) {
        int t = (threadIdx.x >= (unsigned)off) ? lds[threadIdx.x - off] : 0;
        __syncthreads();
        lds[threadIdx.x] += t;
        __syncthreads();
    }
    if (i < N) rowptr[i + 1] = lds[threadIdx.x];
    if (threadIdx.x == SCAN_B - 1) bsum[blockIdx.x] = lds[threadIdx.x];
}

__global__ void scan2_kernel(int* __restrict__ bsum, int nb) {
    int lane = threadIdx.x;  // 64 threads
    int carry = 0;
    for (int base = 0; base < nb; base += 64) {
        int i = base + lane;
        int orig = (i < nb) ? bsum[i] : 0;
        int v = orig;
        for (int off = 1; off < 64; off <<= 1) {
            int t = __shfl_up(v, off);
            if (lane >= off) v += t;
        }
        if (i < nb) bsum[i] = carry + v - orig;  // exclusive
        carry += __shfl(v, 63);
    }
}

__global__ void scan3_kernel(int* __restrict__ rowptr, int* __restrict__ cursor,
                             const int* __restrict__ bsum, int N) {
    int i = blockIdx.x * blockDim.x + threadIdx.x;
    if (i == 0) { rowptr[0] = 0; cursor[0] = 0; }
    if (i < N) {
        int v = rowptr[i + 1] + bsum[i / SCAN_B];
        rowptr[i + 1] = v;
        if (i + 1 < N) cursor[i + 1] = v;
    }
}

// pack (src, x[src]) into one 8B store: ONE dirty cache line per edge instead of two
__global__ void fill_kernel(const int* __restrict__ src, const int* __restrict__ dst,
                            const int* __restrict__ x, int* __restrict__ cursor,
                            int2* __restrict__ col2, int E) {
    int e = blockIdx.x * blockDim.x + threadIdx.x;
    if (e >= E) return;
    int d = dst[e];
    int s = src[e];
    int xs = x[s];
    int pos = atomicAdd(&cursor[d], 1);
    long long packed = (unsigned int)s | ((long long)(unsigned int)xs << 32);
    *(long long*)&col2[pos] = packed;   // .x = s, .y = x[s]
}

// ================= GCN: h1[v] = relu( sum_{u in N_in(v)} embW[x[u]] ) =================

__global__ __launch_bounds__(256) void gcn_kernel(const int* __restrict__ rowptr,
                                                  const int2* __restrict__ col2,
                                                  const float* __restrict__ embW,
                                                  float* __restrict__ h1, int N, int V) {
    extern __shared__ float lembW[];
    int tid = threadIdx.x;
    for (int i = tid; i < V * D; i += 256) lembW[i] = embW[i];
    __syncthreads();
    int lane = tid & 63;
    int wid = (blockIdx.x * 256 + tid) >> 6;
    int stride = (gridDim.x * 256) >> 6;
    for (int v = wid; v < N; v += stride) {
        int beg = rowptr[v], end = rowptr[v + 1];
        float acc = 0.f;
        int e = beg;
        for (; e + 8 <= end; e += 8) {
            float f0 = lembW[col2[e + 0].y * D + lane];
            float f1 = lembW[col2[e + 1].y * D + lane];
            float f2 = lembW[col2[e + 2].y * D + lane];
            float f3 = lembW[col2[e + 3].y * D + lane];
            float f4 = lembW[col2[e + 4].y * D + lane];
            float f5 = lembW[col2[e + 5].y * D + lane];
            float f6 = lembW[col2[e + 6].y * D + lane];
            float f7 = lembW[col2[e + 7].y * D + lane];
            acc += f0; acc += f1; acc += f2; acc += f3;
            acc += f4; acc += f5; acc += f6; acc += f7;
        }
        for (; e < end; ++e) acc += lembW[col2[e].y * D + lane];
        h1[(size_t)v * D + lane] = fmaxf(acc, 0.f);
    }
}

// ================= SAGE epilogue: h2 = relu( agg(A)/deg + B ) =================

__global__ __launch_bounds__(256) void sage_agg_kernel(const int* __restrict__ rowptr,
                                                       const int2* __restrict__ col2,
                                                       const float* __restrict__ A,
                                                       const float* __restrict__ B,
                                                       float* __restrict__ h2, int N) {
    int tid = threadIdx.x;
    int lane = tid & 63;
    int v = blockIdx.x * 4 + (tid >> 6);
    if (v >= N) return;
    int beg = rowptr[v], end = rowptr[v + 1];
    float acc = 0.f;
    int e = beg;
    for (; e + 8 <= end; e += 8) {
        float f0 = A[(size_t)col2[e + 0].x * D + lane];
        float f1 = A[(size_t)col2[e + 1].x * D + lane];
        float f2 = A[(size_t)col2[e + 2].x * D + lane];
        float f3 = A[(size_t)col2[e + 3].x * D + lane];
        float f4 = A[(size_t)col2[e + 4].x * D + lane];
        float f5 = A[(size_t)col2[e + 5].x * D + lane];
        float f6 = A[(size_t)col2[e + 6].x * D + lane];
        float f7 = A[(size_t)col2[e + 7].x * D + lane];
        acc += f0; acc += f1; acc += f2; acc += f3;
        acc += f4; acc += f5; acc += f6; acc += f7;
    }
    for (; e < end; ++e) acc += A[(size_t)col2[e].x * D + lane];
    float inv = 1.f / fmaxf((float)(end - beg), 1.f);
    h2[(size_t)v * D + lane] = fmaxf(acc * inv + B[(size_t)v * D + lane], 0.f);
}

// ================= GIN epilogue: t = relu( C + agg(C) + b1 ) =================

__global__ __launch_bounds__(256) void gin_agg_kernel(const int* __restrict__ rowptr,
                                                      const int2* __restrict__ col2,
                                                      const float* __restrict__ C,
                                                      const float* __restrict__ b1,
                                                      float* __restrict__ t, int N) {
    int tid = threadIdx.x;
    int lane = tid & 63;
    int v = blockIdx.x * 4 + (tid >> 6);
    if (v >= N) return;
    int beg = rowptr[v], end = rowptr[v + 1];
    float acc = 0.f;
    int e = beg;
    for (; e + 8 <= end; e += 8) {
        float f0 = C[(size_t)col2[e + 0].x * D + lane];
        float f1 = C[(size_t)col2[e + 1].x * D + lane];
        float f2 = C[(size_t)col2[e + 2].x * D + lane];
        float f3 = C[(size_t)col2[e + 3].x * D + lane];
        float f4 = C[(size_t)col2[e + 4].x * D + lane];
        float f5 = C[(size_t)col2[e + 5].x * D + lane];
        float f6 = C[(size_t)col2[e + 6].x * D + lane];
        float f7 = C[(size_t)col2[e + 7].x * D + lane];
        acc += f0; acc += f1; acc += f2; acc += f3;
        acc += f4; acc += f5; acc += f6; acc += f7;
    }
    for (; e < end; ++e) acc += C[(size_t)col2[e].x * D + lane];
    size_t idx = (size_t)v * D + lane;
    t[idx] = fmaxf(C[idx] + acc + b1[lane], 0.f);
}

// ================= pooling (boundary search fused in) =================

__global__ void pool_final_kernel(const float* __restrict__ h1, const float* __restrict__ h2,
                                  const float* __restrict__ h3,
                                  const int* __restrict__ batch, int N,
                                  const float* __restrict__ W1, const float* __restrict__ W2,
                                  const float* __restrict__ W3, float* __restrict__ out, int G) {
    int g = blockIdx.x;
    int lane = threadIdx.x;  // 64
    int lo = 0, hi = N;
    while (lo < hi) { int mid = (lo + hi) >> 1; if (batch[mid] < g) lo = mid + 1; else hi = mid; }
    int beg = lo;
    hi = N;
    while (lo < hi) { int mid = (lo + hi) >> 1; if (batch[mid] < g + 1) lo = mid + 1; else hi = mid; }
    int end = lo;

    float s1 = 0.f, s2 = 0.f, s3 = 0.f;
    for (int v = beg; v < end; ++v) {
        s1 += h1[(size_t)v * D + lane];
        s2 += h2[(size_t)v * D + lane];
        s3 += h3[(size_t)v * D + lane];
    }
    float inv = 1.f / fmaxf((float)(end - beg), 1.f);
    float p1 = s1 * inv, p2 = s2 * inv, p3 = s3 * inv;
    float acc = 0.f;
#pragma unroll
    for (int k = 0; k < D; ++k) {
        acc += __shfl(p1, k) * W1[k * D + lane]
             + __shfl(p2, k) * W2[k * D + lane]
             + __shfl(p3, k) * W3[k * D + lane];
    }
    out[(size_t)g * D + lane] = fmaxf(acc, 0.f);
}

// ================= launch =================

static inline size_t align256(size_t x) { return (x + 255) & ~(size_t)255; }

extern "C" void kernel_launch(void* const* d_in, const int* in_sizes, int n_in,
                              void* d_out, int out_size, void* d_ws, size_t ws_size,
                              hipStream_t stream) {
    const int* x      = (const int*)d_in[0];
    const int* ei     = (const int*)d_in[1];
    const int* batch  = (const int*)d_in[2];
    const float* emb  = (const float*)d_in[3];
    const float* Wgcn = (const float*)d_in[4];
    const float* Wsl  = (const float*)d_in[5];
    const float* Wsr  = (const float*)d_in[6];
    const float* Wg1  = (const float*)d_in[7];
    const float* bg1  = (const float*)d_in[8];
    const float* Wg2  = (const float*)d_in[9];
    const float* bg2  = (const float*)d_in[10];
    const float* Wp1  = (const float*)d_in[11];
    const float* Wp2  = (const float*)d_in[12];
    const float* Wp3  = (const float*)d_in[13];
    float* out = (float*)d_out;

    const int N = in_sizes[0];
    const int E = in_sizes[1] / 2;
    const int V = in_sizes[3] / D;
    const int G = out_size / D;
    const int* src = ei;
    const int* dst = ei + E;

    const int NB = (N + SCAN_B - 1) / SCAN_B;

    // workspace layout
    char* base = (char*)d_ws;
    size_t off = 0;
    float* embW   = (float*)(base + off); off = align256(off + (size_t)V * D * 4);
    int*   deg    = (int*)(base + off);   off = align256(off + (size_t)N * 4);
    int*   rowptr = (int*)(base + off);   off = align256(off + (size_t)(N + 1) * 4);
    int*   cursor = (int*)(base + off);   off = align256(off + (size_t)N * 4);
    int*   bsum   = (int*)(base + off);   off = align256(off + (size_t)NB * 4);
    int2*  col2   = (int2*)(base + off);  off = align256(off + (size_t)E * 8);
    float* h1     = (float*)(base + off); off = align256(off + (size_t)N * D * 4);
    float* h2     = (float*)(base + off); off = align256(off + (size_t)N * D * 4);
    float* h3     = (float*)(base + off); off = align256(off + (size_t)N * D * 4);
    float* A      = (float*)(base + off); off = align256(off + (size_t)N * D * 4);
    float* B      = (float*)(base + off); off = align256(off + (size_t)N * D * 4);
    (void)ws_size;

    float* C = A;   // reuse: A dead after sage_agg
    float* t = B;   // reuse: B dead after sage_agg

    hipMemsetAsync(deg, 0, (size_t)N * 4, stream);

    // embW = emb @ Wgcn
    gemm64_kernel<<<(V + 63) / 64, 256, 0, stream>>>(emb, V, Wgcn, nullptr, nullptr, 0, embW, nullptr);

    int eb = (E + 255) / 256;
    deg_kernel<<<eb, 256, 0, stream>>>(dst, deg, E);
    scan1_kernel<<<NB, SCAN_B, 0, stream>>>(deg, rowptr, bsum, N);
    scan2_kernel<<<1, 64, 0, stream>>>(bsum, NB);
    int nb256 = (N + 255) / 256;
    scan3_kernel<<<nb256, 256, 0, stream>>>(rowptr, cursor, bsum, N);
    fill_kernel<<<eb, 256, 0, stream>>>(src, dst, x, cursor, col2, E);

    // GCN gather
    gcn_kernel<<<2048, 256, (size_t)V * D * 4, stream>>>(rowptr, col2, embW, h1, N, V);

    // SAGE: A = h1@Wl, B = h1@Wr (dual GEMM), then fused agg epilogue
    int gb = (N + 63) / 64;
    gemm64_kernel<<<gb, 256, 0, stream>>>(h1, N, Wsl, Wsr, nullptr, 0, A, B);
    sage_agg_kernel<<<(N + 3) / 4, 256, 0, stream>>>(rowptr, col2, A, B, h2, N);

    // GIN: C = h2@W1, t = relu(C + agg(C) + b1), h3 = relu(t@W2 + b2)
    gemm64_kernel<<<gb, 256, 0, stream>>>(h2, N, Wg1, nullptr, nullptr, 0, C, nullptr);
    gin_agg_kernel<<<(N + 3) / 4, 256, 0, stream>>>(rowptr, col2, C, bg1, t, N);
    gemm64_kernel<<<gb, 256, 0, stream>>>(t, N, Wg2, nullptr, bg2, 1, h3, nullptr);

    // pooling (gstart fused into pool_final)
    pool_final_kernel<<<G, D, 0, stream>>>(h1, h2, h3, batch, N, Wp1, Wp2, Wp3, out, G);
}

// Round 4
// 337.814 us; speedup vs baseline: 1.1756x; 1.1756x over previous
//
#include <hip/hip_runtime.h>
#include <hip/hip_bf16.h>

#define D 64
#define K3E 4096

// Edge word packing (requires N <= 65536, V <= 128 — true for this problem):
//   bits [0:15]  = src node
//   bits [16:22] = x[src]   (vocab id)
//   bits [23:30] = dst & 255 (node index within its 256-node bucket)

// ================= register-tiled fp32 GEMM: out = act(in[nrows x 64] @ W + bias) =================

__global__ __launch_bounds__(256) void gemm64_kernel(
    const float* __restrict__ in, int nrows,
    const float* __restrict__ W1, const float* __restrict__ W2,
    const float* __restrict__ bias, int do_relu,
    float* __restrict__ out1, float* __restrict__ out2)
{
    __shared__ float At[64][68];
    __shared__ float Ws1[64][64];
    __shared__ float Ws2[64][64];
    int tid = threadIdx.x;
    {
        const float4* w1v = (const float4*)W1;
        float4* s1 = (float4*)&Ws1[0][0];
        for (int i = tid; i < 1024; i += 256) s1[i] = w1v[i];
        if (W2) {
            const float4* w2v = (const float4*)W2;
            float4* s2 = (float4*)&Ws2[0][0];
            for (int i = tid; i < 1024; i += 256) s2[i] = w2v[i];
        }
    }
    int r0 = blockIdx.x * 64;
    for (int i = tid; i < 1024; i += 256) {
        int r = i >> 4, c4 = i & 15;
        int gr = r0 + r; if (gr >= nrows) gr = nrows - 1;
        float4 v = ((const float4*)(in + (size_t)gr * D))[c4];
        float* dp = &At[r][c4 * 4];
        dp[0] = v.x; dp[1] = v.y; dp[2] = v.z; dp[3] = v.w;
    }
    __syncthreads();

    int cg = tid & 15;
    int rg = tid >> 4;
    float acc1[4][4] = {{0.f}}, acc2[4][4] = {{0.f}};

    for (int k0 = 0; k0 < 64; k0 += 4) {
        float4 a[4], w1[4];
#pragma unroll
        for (int i = 0; i < 4; ++i) a[i] = *(const float4*)&At[4 * rg + i][k0];
#pragma unroll
        for (int j = 0; j < 4; ++j) w1[j] = *(const float4*)&Ws1[k0 + j][cg * 4];
#pragma unroll
        for (int i = 0; i < 4; ++i) {
            float av[4] = {a[i].x, a[i].y, a[i].z, a[i].w};
#pragma unroll
            for (int kk = 0; kk < 4; ++kk) {
                acc1[i][0] += av[kk] * w1[kk].x;
                acc1[i][1] += av[kk] * w1[kk].y;
                acc1[i][2] += av[kk] * w1[kk].z;
                acc1[i][3] += av[kk] * w1[kk].w;
            }
        }
        if (W2) {
            float4 w2[4];
#pragma unroll
            for (int j = 0; j < 4; ++j) w2[j] = *(const float4*)&Ws2[k0 + j][cg * 4];
#pragma unroll
            for (int i = 0; i < 4; ++i) {
                float av[4] = {a[i].x, a[i].y, a[i].z, a[i].w};
#pragma unroll
                for (int kk = 0; kk < 4; ++kk) {
                    acc2[i][0] += av[kk] * w2[kk].x;
                    acc2[i][1] += av[kk] * w2[kk].y;
                    acc2[i][2] += av[kk] * w2[kk].z;
                    acc2[i][3] += av[kk] * w2[kk].w;
                }
            }
        }
    }

    float4 bv = make_float4(0.f, 0.f, 0.f, 0.f);
    if (bias) bv = ((const float4*)bias)[cg];
#pragma unroll
    for (int i = 0; i < 4; ++i) {
        int gr = r0 + 4 * rg + i;
        if (gr < nrows) {
            float4 o;
            o.x = acc1[i][0] + bv.x; o.y = acc1[i][1] + bv.y;
            o.z = acc1[i][2] + bv.z; o.w = acc1[i][3] + bv.w;
            if (do_relu) {
                o.x = fmaxf(o.x, 0.f); o.y = fmaxf(o.y, 0.f);
                o.z = fmaxf(o.z, 0.f); o.w = fmaxf(o.w, 0.f);
            }
            ((float4*)(out1 + (size_t)gr * D))[cg] = o;
            if (out2) {
                float4 o2;
                o2.x = acc2[i][0]; o2.y = acc2[i][1]; o2.z = acc2[i][2]; o2.w = acc2[i][3];
                ((float4*)(out2 + (size_t)gr * D))[cg] = o2;
            }
        }
    }
}

// ================= bucketed CSR build =================

// K1: global histogram over 256-node buckets (LDS-aggregated)
__global__ __launch_bounds__(256) void bucket_count_kernel(const int* __restrict__ dst, int E,
                                                           int* __restrict__ bucketCount) {
    __shared__ int hist[256];
    int t = threadIdx.x;
    hist[t] = 0;
    __syncthreads();
    for (int e = blockIdx.x * 256 + t; e < E; e += gridDim.x * 256)
        atomicAdd(&hist[dst[e] >> 8], 1);
    __syncthreads();
    int c = hist[t];
    if (c) atomicAdd(&bucketCount[t], c);
}

// K2: exclusive scan of 256 bucket counts -> bases + cursors
__global__ void bucket_scan_kernel(const int* __restrict__ bucketCount,
                                   int* __restrict__ bucketBase, int* __restrict__ bucketCursor) {
    __shared__ int lds[256];
    int t = threadIdx.x;
    int c = bucketCount[t];
    lds[t] = c;
    __syncthreads();
    for (int off = 1; off < 256; off <<= 1) {
        int v = (t >= off) ? lds[t - off] : 0;
        __syncthreads();
        lds[t] += v;
        __syncthreads();
    }
    int excl = lds[t] - c;
    bucketBase[t] = excl;
    bucketCursor[t] = excl;
    if (t == 255) bucketBase[256] = lds[t];
}

// K3: scatter packed edges into their bucket region, one contiguous run per (block,bucket)
__global__ __launch_bounds__(256) void scatter_kernel(const int* __restrict__ src,
                                                      const int* __restrict__ dst,
                                                      const int* __restrict__ x,
                                                      int* __restrict__ bucketCursor,
                                                      int* __restrict__ ebuf, int E) {
    __shared__ int uu[K3E];
    __shared__ unsigned char bb[K3E];
    __shared__ int hist[256];
    __shared__ int resBase[256];
    int t = threadIdx.x;
    hist[t] = 0;
    __syncthreads();
    int e0 = blockIdx.x * K3E;
    int cnt = E - e0; if (cnt > K3E) cnt = K3E;
    for (int i = t; i < cnt; i += 256) {
        int e = e0 + i;
        int s = src[e];
        int d = dst[e];
        int xs = x[s];
        uu[i] = s | (xs << 16) | ((d & 255) << 23);
        int b = d >> 8;
        bb[i] = (unsigned char)b;
        atomicAdd(&hist[b], 1);
    }
    __syncthreads();
    int c = hist[t];
    if (c) resBase[t] = atomicAdd(&bucketCursor[t], c);
    __syncthreads();
    hist[t] = 0;
    __syncthreads();
    for (int i = t; i < cnt; i += 256) {
        int b = bb[i];
        int r = atomicAdd(&hist[b], 1);
        ebuf[resBase[b] + r] = uu[i];
    }
}

// K4: per-bucket exact CSR (LDS histogram + scan over the bucket's 256 nodes)
__global__ __launch_bounds__(256) void csr_kernel(const int* __restrict__ ebuf,
                                                  const int* __restrict__ bucketBase,
                                                  int* __restrict__ rowptr, int* __restrict__ col,
                                                  int N, int E) {
    __shared__ int hist[256];
    __shared__ int sc[256];
    int b = blockIdx.x, t = threadIdx.x;
    int base = bucketBase[b], endb = bucketBase[b + 1];
    int m = endb - base;
    hist[t] = 0;
    __syncthreads();
    for (int i = t; i < m; i += 256)
        atomicAdd(&hist[(ebuf[base + i] >> 23) & 255], 1);
    __syncthreads();
    int v = hist[t];
    sc[t] = v;
    __syncthreads();
    for (int off = 1; off < 256; off <<= 1) {
        int w = (t >= off) ? sc[t - off] : 0;
        __syncthreads();
        sc[t] += w;
        __syncthreads();
    }
    int excl = sc[t] - v;
    int node = (b << 8) + t;
    if (node < N) rowptr[node] = base + excl;
    if (b == gridDim.x - 1 && t == 0) rowptr[N] = E;
    __syncthreads();
    hist[t] = excl;   // running local cursor
    __syncthreads();
    for (int i = t; i < m; i += 256) {
        int u = ebuf[base + i];
        int dl = (u >> 23) & 255;
        int r = atomicAdd(&hist[dl], 1);
        col[base + r] = u;
    }
}

// ================= GCN: h1[v] = relu( sum_{u in N_in(v)} embW[x[u]] ) =================

__global__ __launch_bounds__(256) void gcn_kernel(const int* __restrict__ rowptr,
                                                  const int* __restrict__ col,
                                                  const float* __restrict__ embW,
                                                  float* __restrict__ h1, int N, int V) {
    extern __shared__ float lembW[];
    int tid = threadIdx.x;
    for (int i = tid; i < V * D; i += 256) lembW[i] = embW[i];
    __syncthreads();
    int lane = tid & 63;
    int wid = (blockIdx.x * 256 + tid) >> 6;
    int stride = (gridDim.x * 256) >> 6;
    for (int v = wid; v < N; v += stride) {
        int beg = rowptr[v], end = rowptr[v + 1];
        float acc = 0.f;
        int e = beg;
        for (; e + 8 <= end; e += 8) {
            float f0 = lembW[((col[e + 0] >> 16) & 0x7F) * D + lane];
            float f1 = lembW[((col[e + 1] >> 16) & 0x7F) * D + lane];
            float f2 = lembW[((col[e + 2] >> 16) & 0x7F) * D + lane];
            float f3 = lembW[((col[e + 3] >> 16) & 0x7F) * D + lane];
            float f4 = lembW[((col[e + 4] >> 16) & 0x7F) * D + lane];
            float f5 = lembW[((col[e + 5] >> 16) & 0x7F) * D + lane];
            float f6 = lembW[((col[e + 6] >> 16) & 0x7F) * D + lane];
            float f7 = lembW[((col[e + 7] >> 16) & 0x7F) * D + lane];
            acc += f0; acc += f1; acc += f2; acc += f3;
            acc += f4; acc += f5; acc += f6; acc += f7;
        }
        for (; e < end; ++e) acc += lembW[((col[e] >> 16) & 0x7F) * D + lane];
        h1[(size_t)v * D + lane] = fmaxf(acc, 0.f);
    }
}

// ================= SAGE epilogue: h2 = relu( agg(A)/deg + B ) =================

__global__ __launch_bounds__(256) void sage_agg_kernel(const int* __restrict__ rowptr,
                                                       const int* __restrict__ col,
                                                       const float* __restrict__ A,
                                                       const float* __restrict__ B,
                                                       float* __restrict__ h2, int N) {
    int tid = threadIdx.x;
    int lane = tid & 63;
    int v = blockIdx.x * 4 + (tid >> 6);
    if (v >= N) return;
    int beg = rowptr[v], end = rowptr[v + 1];
    float acc = 0.f;
    int e = beg;
    for (; e + 8 <= end; e += 8) {
        float f0 = A[(size_t)(col[e + 0] & 0xFFFF) * D + lane];
        float f1 = A[(size_t)(col[e + 1] & 0xFFFF) * D + lane];
        float f2 = A[(size_t)(col[e + 2] & 0xFFFF) * D + lane];
        float f3 = A[(size_t)(col[e + 3] & 0xFFFF) * D + lane];
        float f4 = A[(size_t)(col[e + 4] & 0xFFFF) * D + lane];
        float f5 = A[(size_t)(col[e + 5] & 0xFFFF) * D + lane];
        float f6 = A[(size_t)(col[e + 6] & 0xFFFF) * D + lane];
        float f7 = A[(size_t)(col[e + 7] & 0xFFFF) * D + lane];
        acc += f0; acc += f1; acc += f2; acc += f3;
        acc += f4; acc += f5; acc += f6; acc += f7;
    }
    for (; e < end; ++e) acc += A[(size_t)(col[e] & 0xFFFF) * D + lane];
    float inv = 1.f / fmaxf((float)(end - beg), 1.f);
    h2[(size_t)v * D + lane] = fmaxf(acc * inv + B[(size_t)v * D + lane], 0.f);
}

// ================= GIN epilogue: t = relu( C + agg(C) + b1 ) =================

__global__ __launch_bounds__(256) void gin_agg_kernel(const int* __restrict__ rowptr,
                                                      const int* __restrict__ col,
                                                      const float* __restrict__ C,
                                                      const float* __restrict__ b1,
                                                      float* __restrict__ t, int N) {
    int tid = threadIdx.x;
    int lane = tid & 63;
    int v = blockIdx.x * 4 + (tid >> 6);
    if (v >= N) return;
    int beg = rowptr[v], end = rowptr[v + 1];
    float acc = 0.f;
    int e = beg;
    for (; e + 8 <= end; e += 8) {
        float f0 = C[(size_t)(col[e + 0] & 0xFFFF) * D + lane];
        float f1 = C[(size_t)(col[e + 1] & 0xFFFF) * D + lane];
        float f2 = C[(size_t)(col[e + 2] & 0xFFFF) * D + lane];
        float f3 = C[(size_t)(col[e + 3] & 0xFFFF) * D + lane];
        float f4 = C[(size_t)(col[e + 4] & 0xFFFF) * D + lane];
        float f5 = C[(size_t)(col[e + 5] & 0xFFFF) * D + lane];
        float f6 = C[(size_t)(col[e + 6] & 0xFFFF) * D + lane];
        float f7 = C[(size_t)(col[e + 7] & 0xFFFF) * D + lane];
        acc += f0; acc += f1; acc += f2; acc += f3;
        acc += f4; acc += f5; acc += f6; acc += f7;
    }
    for (; e < end; ++e) acc += C[(size_t)(col[e] & 0xFFFF) * D + lane];
    size_t idx = (size_t)v * D + lane;
    t[idx] = fmaxf(C[idx] + acc + b1[lane], 0.f);
}

// ================= pooling (boundary search fused in) =================

__global__ void pool_final_kernel(const float* __restrict__ h1, const float* __restrict__ h2,
                                  const float* __restrict__ h3,
                                  const int* __restrict__ batch, int N,
                                  const float* __restrict__ W1, const float* __restrict__ W2,
                                  const float* __restrict__ W3, float* __restrict__ out, int G) {
    int g = blockIdx.x;
    int lane = threadIdx.x;  // 64
    int lo = 0, hi = N;
    while (lo < hi) { int mid = (lo + hi) >> 1; if (batch[mid] < g) lo = mid + 1; else hi = mid; }
    int beg = lo;
    hi = N;
    while (lo < hi) { int mid = (lo + hi) >> 1; if (batch[mid] < g + 1) lo = mid + 1; else hi = mid; }
    int end = lo;

    float s1 = 0.f, s2 = 0.f, s3 = 0.f;
    for (int v = beg; v < end; ++v) {
        s1 += h1[(size_t)v * D + lane];
        s2 += h2[(size_t)v * D + lane];
        s3 += h3[(size_t)v * D + lane];
    }
    float inv = 1.f / fmaxf((float)(end - beg), 1.f);
    float p1 = s1 * inv, p2 = s2 * inv, p3 = s3 * inv;
    float acc = 0.f;
#pragma unroll
    for (int k = 0; k < D; ++k) {
        acc += __shfl(p1, k) * W1[k * D + lane]
             + __shfl(p2, k) * W2[k * D + lane]
             + __shfl(p3, k) * W3[k * D + lane];
    }
    out[(size_t)g * D + lane] = fmaxf(acc, 0.f);
}

// ================= launch =================

static inline size_t align256(size_t x) { return (x + 255) & ~(size_t)255; }

extern "C" void kernel_launch(void* const* d_in, const int* in_sizes, int n_in,
                              void* d_out, int out_size, void* d_ws, size_t ws_size,
                              hipStream_t stream) {
    const int* x      = (const int*)d_in[0];
    const int* ei     = (const int*)d_in[1];
    const int* batch  = (const int*)d_in[2];
    const float* emb  = (const float*)d_in[3];
    const float* Wgcn = (const float*)d_in[4];
    const float* Wsl  = (const float*)d_in[5];
    const float* Wsr  = (const float*)d_in[6];
    const float* Wg1  = (const float*)d_in[7];
    const float* bg1  = (const float*)d_in[8];
    const float* Wg2  = (const float*)d_in[9];
    const float* bg2  = (const float*)d_in[10];
    const float* Wp1  = (const float*)d_in[11];
    const float* Wp2  = (const float*)d_in[12];
    const float* Wp3  = (const float*)d_in[13];
    float* out = (float*)d_out;

    const int N = in_sizes[0];
    const int E = in_sizes[1] / 2;
    const int V = in_sizes[3] / D;
    const int G = out_size / D;
    const int* src = ei;
    const int* dst = ei + E;
    const int NBUCK = (N + 255) >> 8;

    // workspace layout
    char* base = (char*)d_ws;
    size_t off = 0;
    float* embW    = (float*)(base + off); off = align256(off + (size_t)V * D * 4);
    int* bucketCount  = (int*)(base + off); off = align256(off + 256 * 4);
    int* bucketBase   = (int*)(base + off); off = align256(off + 257 * 4);
    int* bucketCursor = (int*)(base + off); off = align256(off + 256 * 4);
    int* rowptr    = (int*)(base + off);   off = align256(off + (size_t)(N + 1) * 4);
    int* ebuf      = (int*)(base + off);   off = align256(off + (size_t)E * 4);
    int* col       = (int*)(base + off);   off = align256(off + (size_t)E * 4);
    float* h1      = (float*)(base + off); off = align256(off + (size_t)N * D * 4);
    float* h2      = (float*)(base + off); off = align256(off + (size_t)N * D * 4);
    float* h3      = (float*)(base + off); off = align256(off + (size_t)N * D * 4);
    float* A       = (float*)(base + off); off = align256(off + (size_t)N * D * 4);
    float* B       = (float*)(base + off); off = align256(off + (size_t)N * D * 4);
    (void)ws_size;

    float* C = A;   // reuse: A dead after sage_agg
    float* t = B;   // reuse: B dead after sage_agg

    hipMemsetAsync(bucketCount, 0, 256 * 4, stream);

    // embW = emb @ Wgcn
    gemm64_kernel<<<(V + 63) / 64, 256, 0, stream>>>(emb, V, Wgcn, nullptr, nullptr, 0, embW, nullptr);

    // CSR build (bucketed)
    bucket_count_kernel<<<256, 256, 0, stream>>>(dst, E, bucketCount);
    bucket_scan_kernel<<<1, 256, 0, stream>>>(bucketCount, bucketBase, bucketCursor);
    scatter_kernel<<<(E + K3E - 1) / K3E, 256, 0, stream>>>(src, dst, x, bucketCursor, ebuf, E);
    csr_kernel<<<NBUCK, 256, 0, stream>>>(ebuf, bucketBase, rowptr, col, N, E);

    // GCN gather
    gcn_kernel<<<2048, 256, (size_t)V * D * 4, stream>>>(rowptr, col, embW, h1, N, V);

    // SAGE: A = h1@Wl, B = h1@Wr (dual GEMM), then fused agg epilogue
    int gb = (N + 63) / 64;
    gemm64_kernel<<<gb, 256, 0, stream>>>(h1, N, Wsl, Wsr, nullptr, 0, A, B);
    sage_agg_kernel<<<(N + 3) / 4, 256, 0, stream>>>(rowptr, col, A, B, h2, N);

    // GIN: C = h2@W1, t = relu(C + agg(C) + b1), h3 = relu(t@W2 + b2)
    gemm64_kernel<<<gb, 256, 0, stream>>>(h2, N, Wg1, nullptr, nullptr, 0, C, nullptr);
    gin_agg_kernel<<<(N + 3) / 4, 256, 0, stream>>>(rowptr, col, C, bg1, t, N);
    gemm64_kernel<<<gb, 256, 0, stream>>>(t, N, Wg2, nullptr, bg2, 1, h3, nullptr);

    // pooling (gstart fused into pool_final)
    pool_final_kernel<<<G, D, 0, stream>>>(h1, h2, h3, batch, N, Wp1, Wp2, Wp3, out, G);
}

// Round 5
// 307.000 us; speedup vs baseline: 1.2936x; 1.1004x over previous
//
#include <hip/hip_runtime.h>
#include <hip/hip_bf16.h>

#define D 64
#define K3E 4096

// Edge word packing (requires N <= 65536, V <= 128 — true for this problem):
//   bits [0:15]  = src node
//   bits [16:22] = x[src]   (vocab id)
//   bits [23:30] = dst & 255 (node index within its 256-node bucket)

// ================= register-tiled fp32 GEMM: out = act(in[nrows x 64] @ W + bias) =================

__global__ __launch_bounds__(256) void gemm64_kernel(
    const float* __restrict__ in, int nrows,
    const float* __restrict__ W1, const float* __restrict__ W2,
    const float* __restrict__ bias, int do_relu,
    float* __restrict__ out1, float* __restrict__ out2)
{
    __shared__ float At[64][68];
    __shared__ float Ws1[64][64];
    __shared__ float Ws2[64][64];
    int tid = threadIdx.x;
    {
        const float4* w1v = (const float4*)W1;
        float4* s1 = (float4*)&Ws1[0][0];
        for (int i = tid; i < 1024; i += 256) s1[i] = w1v[i];
        if (W2) {
            const float4* w2v = (const float4*)W2;
            float4* s2 = (float4*)&Ws2[0][0];
            for (int i = tid; i < 1024; i += 256) s2[i] = w2v[i];
        }
    }
    int r0 = blockIdx.x * 64;
    for (int i = tid; i < 1024; i += 256) {
        int r = i >> 4, c4 = i & 15;
        int gr = r0 + r; if (gr >= nrows) gr = nrows - 1;
        float4 v = ((const float4*)(in + (size_t)gr * D))[c4];
        float* dp = &At[r][c4 * 4];
        dp[0] = v.x; dp[1] = v.y; dp[2] = v.z; dp[3] = v.w;
    }
    __syncthreads();

    int cg = tid & 15;
    int rg = tid >> 4;
    float acc1[4][4] = {{0.f}}, acc2[4][4] = {{0.f}};

    for (int k0 = 0; k0 < 64; k0 += 4) {
        float4 a[4], w1[4];
#pragma unroll
        for (int i = 0; i < 4; ++i) a[i] = *(const float4*)&At[4 * rg + i][k0];
#pragma unroll
        for (int j = 0; j < 4; ++j) w1[j] = *(const float4*)&Ws1[k0 + j][cg * 4];
#pragma unroll
        for (int i = 0; i < 4; ++i) {
            float av[4] = {a[i].x, a[i].y, a[i].z, a[i].w};
#pragma unroll
            for (int kk = 0; kk < 4; ++kk) {
                acc1[i][0] += av[kk] * w1[kk].x;
                acc1[i][1] += av[kk] * w1[kk].y;
                acc1[i][2] += av[kk] * w1[kk].z;
                acc1[i][3] += av[kk] * w1[kk].w;
            }
        }
        if (W2) {
            float4 w2[4];
#pragma unroll
            for (int j = 0; j < 4; ++j) w2[j] = *(const float4*)&Ws2[k0 + j][cg * 4];
#pragma unroll
            for (int i = 0; i < 4; ++i) {
                float av[4] = {a[i].x, a[i].y, a[i].z, a[i].w};
#pragma unroll
                for (int kk = 0; kk < 4; ++kk) {
                    acc2[i][0] += av[kk] * w2[kk].x;
                    acc2[i][1] += av[kk] * w2[kk].y;
                    acc2[i][2] += av[kk] * w2[kk].z;
                    acc2[i][3] += av[kk] * w2[kk].w;
                }
            }
        }
    }

    float4 bv = make_float4(0.f, 0.f, 0.f, 0.f);
    if (bias) bv = ((const float4*)bias)[cg];
#pragma unroll
    for (int i = 0; i < 4; ++i) {
        int gr = r0 + 4 * rg + i;
        if (gr < nrows) {
            float4 o;
            o.x = acc1[i][0] + bv.x; o.y = acc1[i][1] + bv.y;
            o.z = acc1[i][2] + bv.z; o.w = acc1[i][3] + bv.w;
            if (do_relu) {
                o.x = fmaxf(o.x, 0.f); o.y = fmaxf(o.y, 0.f);
                o.z = fmaxf(o.z, 0.f); o.w = fmaxf(o.w, 0.f);
            }
            ((float4*)(out1 + (size_t)gr * D))[cg] = o;
            if (out2) {
                float4 o2;
                o2.x = acc2[i][0]; o2.y = acc2[i][1]; o2.z = acc2[i][2]; o2.w = acc2[i][3];
                ((float4*)(out2 + (size_t)gr * D))[cg] = o2;
            }
        }
    }
}

// ================= bucketed CSR build =================

__global__ __launch_bounds__(256) void bucket_count_kernel(const int* __restrict__ dst, int E,
                                                           int* __restrict__ bucketCount) {
    __shared__ int hist[256];
    int t = threadIdx.x;
    hist[t] = 0;
    __syncthreads();
    for (int e = blockIdx.x * 256 + t; e < E; e += gridDim.x * 256)
        atomicAdd(&hist[dst[e] >> 8], 1);
    __syncthreads();
    int c = hist[t];
    if (c) atomicAdd(&bucketCount[t], c);
}

__global__ void bucket_scan_kernel(const int* __restrict__ bucketCount,
                                   int* __restrict__ bucketBase, int* __restrict__ bucketCursor) {
    __shared__ int lds[256];
    int t = threadIdx.x;
    int c = bucketCount[t];
    lds[t] = c;
    __syncthreads();
    for (int off = 1; off < 256; off <<= 1) {
        int v = (t >= off) ? lds[t - off] : 0;
        __syncthreads();
        lds[t] += v;
        __syncthreads();
    }
    int excl = lds[t] - c;
    bucketBase[t] = excl;
    bucketCursor[t] = excl;
    if (t == 255) bucketBase[256] = lds[t];
}

__global__ __launch_bounds__(256) void scatter_kernel(const int* __restrict__ src,
                                                      const int* __restrict__ dst,
                                                      const int* __restrict__ x,
                                                      int* __restrict__ bucketCursor,
                                                      int* __restrict__ ebuf, int E) {
    __shared__ int uu[K3E];
    __shared__ unsigned char bb[K3E];
    __shared__ int hist[256];
    __shared__ int resBase[256];
    int t = threadIdx.x;
    hist[t] = 0;
    __syncthreads();
    int e0 = blockIdx.x * K3E;
    int cnt = E - e0; if (cnt > K3E) cnt = K3E;
    for (int i = t; i < cnt; i += 256) {
        int e = e0 + i;
        int s = src[e];
        int d = dst[e];
        int xs = x[s];
        uu[i] = s | (xs << 16) | ((d & 255) << 23);
        int b = d >> 8;
        bb[i] = (unsigned char)b;
        atomicAdd(&hist[b], 1);
    }
    __syncthreads();
    int c = hist[t];
    if (c) resBase[t] = atomicAdd(&bucketCursor[t], c);
    __syncthreads();
    hist[t] = 0;
    __syncthreads();
    for (int i = t; i < cnt; i += 256) {
        int b = bb[i];
        int r = atomicAdd(&hist[b], 1);
        ebuf[resBase[b] + r] = uu[i];
    }
}

__global__ __launch_bounds__(256) void csr_kernel(const int* __restrict__ ebuf,
                                                  const int* __restrict__ bucketBase,
                                                  int* __restrict__ rowptr, int* __restrict__ col,
                                                  int N, int E) {
    __shared__ int hist[256];
    __shared__ int sc[256];
    int b = blockIdx.x, t = threadIdx.x;
    int base = bucketBase[b], endb = bucketBase[b + 1];
    int m = endb - base;
    hist[t] = 0;
    __syncthreads();
    for (int i = t; i < m; i += 256)
        atomicAdd(&hist[(ebuf[base + i] >> 23) & 255], 1);
    __syncthreads();
    int v = hist[t];
    sc[t] = v;
    __syncthreads();
    for (int off = 1; off < 256; off <<= 1) {
        int w = (t >= off) ? sc[t - off] : 0;
        __syncthreads();
        sc[t] += w;
        __syncthreads();
    }
    int excl = sc[t] - v;
    int node = (b << 8) + t;
    if (node < N) rowptr[node] = base + excl;
    if (b == gridDim.x - 1 && t == 0) rowptr[N] = E;
    __syncthreads();
    hist[t] = excl;   // running local cursor
    __syncthreads();
    for (int i = t; i < m; i += 256) {
        int u = ebuf[base + i];
        int dl = (u >> 23) & 255;
        int r = atomicAdd(&hist[dl], 1);
        col[base + r] = u;
    }
}

// ================= GCN: h1[v] = relu( sum_{u in N_in(v)} embW[x[u]] ) =================

__global__ __launch_bounds__(256) void gcn_kernel(const int* __restrict__ rowptr,
                                                  const int* __restrict__ col,
                                                  const float* __restrict__ embW,
                                                  float* __restrict__ h1, int N, int V) {
    extern __shared__ float lembW[];
    int tid = threadIdx.x;
    for (int i = tid; i < V * D; i += 256) lembW[i] = embW[i];
    __syncthreads();
    int lane = tid & 63;
    int wid = (blockIdx.x * 256 + tid) >> 6;
    int stride = (gridDim.x * 256) >> 6;
    for (int v = wid; v < N; v += stride) {
        int beg = rowptr[v], end = rowptr[v + 1];
        float acc = 0.f;
        int e = beg;
        for (; e + 8 <= end; e += 8) {
            float f0 = lembW[((col[e + 0] >> 16) & 0x7F) * D + lane];
            float f1 = lembW[((col[e + 1] >> 16) & 0x7F) * D + lane];
            float f2 = lembW[((col[e + 2] >> 16) & 0x7F) * D + lane];
            float f3 = lembW[((col[e + 3] >> 16) & 0x7F) * D + lane];
            float f4 = lembW[((col[e + 4] >> 16) & 0x7F) * D + lane];
            float f5 = lembW[((col[e + 5] >> 16) & 0x7F) * D + lane];
            float f6 = lembW[((col[e + 6] >> 16) & 0x7F) * D + lane];
            float f7 = lembW[((col[e + 7] >> 16) & 0x7F) * D + lane];
            acc += f0; acc += f1; acc += f2; acc += f3;
            acc += f4; acc += f5; acc += f6; acc += f7;
        }
        for (; e < end; ++e) acc += lembW[((col[e] >> 16) & 0x7F) * D + lane];
        h1[(size_t)v * D + lane] = fmaxf(acc, 0.f);
    }
}

// ================= SAGE epilogue: h2 = relu( agg(A)/deg + B ) =================

__global__ __launch_bounds__(256) void sage_agg_kernel(const int* __restrict__ rowptr,
                                                       const int* __restrict__ col,
                                                       const float* __restrict__ A,
                                                       const float* __restrict__ B,
                                                       float* __restrict__ h2, int N) {
    int tid = threadIdx.x;
    int lane = tid & 63;
    int v = blockIdx.x * 4 + (tid >> 6);
    if (v >= N) return;
    int beg = rowptr[v], end = rowptr[v + 1];
    float acc = 0.f;
    int e = beg;
    for (; e + 8 <= end; e += 8) {
        float f0 = A[(size_t)(col[e + 0] & 0xFFFF) * D + lane];
        float f1 = A[(size_t)(col[e + 1] & 0xFFFF) * D + lane];
        float f2 = A[(size_t)(col[e + 2] & 0xFFFF) * D + lane];
        float f3 = A[(size_t)(col[e + 3] & 0xFFFF) * D + lane];
        float f4 = A[(size_t)(col[e + 4] & 0xFFFF) * D + lane];
        float f5 = A[(size_t)(col[e + 5] & 0xFFFF) * D + lane];
        float f6 = A[(size_t)(col[e + 6] & 0xFFFF) * D + lane];
        float f7 = A[(size_t)(col[e + 7] & 0xFFFF) * D + lane];
        acc += f0; acc += f1; acc += f2; acc += f3;
        acc += f4; acc += f5; acc += f6; acc += f7;
    }
    for (; e < end; ++e) acc += A[(size_t)(col[e] & 0xFFFF) * D + lane];
    float inv = 1.f / fmaxf((float)(end - beg), 1.f);
    h2[(size_t)v * D + lane] = fmaxf(acc * inv + B[(size_t)v * D + lane], 0.f);
}

// ================= GIN epilogue: t = relu( C + agg(C) + b1 ) =================

__global__ __launch_bounds__(256) void gin_agg_kernel(const int* __restrict__ rowptr,
                                                      const int* __restrict__ col,
                                                      const float* __restrict__ C,
                                                      const float* __restrict__ b1,
                                                      float* __restrict__ t, int N) {
    int tid = threadIdx.x;
    int lane = tid & 63;
    int v = blockIdx.x * 4 + (tid >> 6);
    if (v >= N) return;
    int beg = rowptr[v], end = rowptr[v + 1];
    float acc = 0.f;
    int e = beg;
    for (; e + 8 <= end; e += 8) {
        float f0 = C[(size_t)(col[e + 0] & 0xFFFF) * D + lane];
        float f1 = C[(size_t)(col[e + 1] & 0xFFFF) * D + lane];
        float f2 = C[(size_t)(col[e + 2] & 0xFFFF) * D + lane];
        float f3 = C[(size_t)(col[e + 3] & 0xFFFF) * D + lane];
        float f4 = C[(size_t)(col[e + 4] & 0xFFFF) * D + lane];
        float f5 = C[(size_t)(col[e + 5] & 0xFFFF) * D + lane];
        float f6 = C[(size_t)(col[e + 6] & 0xFFFF) * D + lane];
        float f7 = C[(size_t)(col[e + 7] & 0xFFFF) * D + lane];
        acc += f0; acc += f1; acc += f2; acc += f3;
        acc += f4; acc += f5; acc += f6; acc += f7;
    }
    for (; e < end; ++e) acc += C[(size_t)(col[e] & 0xFFFF) * D + lane];
    size_t idx = (size_t)v * D + lane;
    t[idx] = fmaxf(C[idx] + acc + b1[lane], 0.f);
}

// ================= pooling: 16 waves per graph + LDS tree reduce =================

__global__ __launch_bounds__(1024) void pool_final_kernel(
    const float* __restrict__ h1, const float* __restrict__ h2,
    const float* __restrict__ h3,
    const int* __restrict__ batch, int N,
    const float* __restrict__ W1, const float* __restrict__ W2,
    const float* __restrict__ W3, float* __restrict__ out, int G) {
    __shared__ float r1[16][64];
    __shared__ float r2[16][64];
    __shared__ float r3[16][64];
    int g = blockIdx.x;
    int tid = threadIdx.x;
    int w = tid >> 6, lane = tid & 63;

    int lo = 0, hi = N;
    while (lo < hi) { int mid = (lo + hi) >> 1; if (batch[mid] < g) lo = mid + 1; else hi = mid; }
    int beg = lo;
    hi = N;
    while (lo < hi) { int mid = (lo + hi) >> 1; if (batch[mid] < g + 1) lo = mid + 1; else hi = mid; }
    int end = lo;

    float s1 = 0.f, s2 = 0.f, s3 = 0.f;
    for (int v = beg + w; v < end; v += 16) {
        size_t idx = (size_t)v * D + lane;
        s1 += h1[idx];
        s2 += h2[idx];
        s3 += h3[idx];
    }
    r1[w][lane] = s1; r2[w][lane] = s2; r3[w][lane] = s3;
    __syncthreads();
#pragma unroll
    for (int stride = 8; stride >= 1; stride >>= 1) {
        if (w < stride) {
            r1[w][lane] += r1[w + stride][lane];
            r2[w][lane] += r2[w + stride][lane];
            r3[w][lane] += r3[w + stride][lane];
        }
        __syncthreads();
    }
    if (w == 0) {
        float inv = 1.f / fmaxf((float)(end - beg), 1.f);
        float p1 = r1[0][lane] * inv, p2 = r2[0][lane] * inv, p3 = r3[0][lane] * inv;
        float acc = 0.f;
#pragma unroll
        for (int k = 0; k < D; ++k) {
            acc += __shfl(p1, k) * W1[k * D + lane]
                 + __shfl(p2, k) * W2[k * D + lane]
                 + __shfl(p3, k) * W3[k * D + lane];
        }
        out[(size_t)g * D + lane] = fmaxf(acc, 0.f);
    }
}

// ================= launch =================

static inline size_t align256(size_t x) { return (x + 255) & ~(size_t)255; }

extern "C" void kernel_launch(void* const* d_in, const int* in_sizes, int n_in,
                              void* d_out, int out_size, void* d_ws, size_t ws_size,
                              hipStream_t stream) {
    const int* x      = (const int*)d_in[0];
    const int* ei     = (const int*)d_in[1];
    const int* batch  = (const int*)d_in[2];
    const float* emb  = (const float*)d_in[3];
    const float* Wgcn = (const float*)d_in[4];
    const float* Wsl  = (const float*)d_in[5];
    const float* Wsr  = (const float*)d_in[6];
    const float* Wg1  = (const float*)d_in[7];
    const float* bg1  = (const float*)d_in[8];
    const float* Wg2  = (const float*)d_in[9];
    const float* bg2  = (const float*)d_in[10];
    const float* Wp1  = (const float*)d_in[11];
    const float* Wp2  = (const float*)d_in[12];
    const float* Wp3  = (const float*)d_in[13];
    float* out = (float*)d_out;

    const int N = in_sizes[0];
    const int E = in_sizes[1] / 2;
    const int V = in_sizes[3] / D;
    const int G = out_size / D;
    const int* src = ei;
    const int* dst = ei + E;
    const int NBUCK = (N + 255) >> 8;

    // workspace layout
    char* base = (char*)d_ws;
    size_t off = 0;
    float* embW    = (float*)(base + off); off = align256(off + (size_t)V * D * 4);
    int* bucketCount  = (int*)(base + off); off = align256(off + 256 * 4);
    int* bucketBase   = (int*)(base + off); off = align256(off + 257 * 4);
    int* bucketCursor = (int*)(base + off); off = align256(off + 256 * 4);
    int* rowptr    = (int*)(base + off);   off = align256(off + (size_t)(N + 1) * 4);
    int* ebuf      = (int*)(base + off);   off = align256(off + (size_t)E * 4);
    int* col       = (int*)(base + off);   off = align256(off + (size_t)E * 4);
    float* h1      = (float*)(base + off); off = align256(off + (size_t)N * D * 4);
    float* h2      = (float*)(base + off); off = align256(off + (size_t)N * D * 4);
    float* h3      = (float*)(base + off); off = align256(off + (size_t)N * D * 4);
    float* A       = (float*)(base + off); off = align256(off + (size_t)N * D * 4);
    float* B       = (float*)(base + off); off = align256(off + (size_t)N * D * 4);
    (void)ws_size;

    float* C = A;   // reuse: A dead after sage_agg
    float* t = B;   // reuse: B dead after sage_agg

    hipMemsetAsync(bucketCount, 0, 256 * 4, stream);

    // embW = emb @ Wgcn
    gemm64_kernel<<<(V + 63) / 64, 256, 0, stream>>>(emb, V, Wgcn, nullptr, nullptr, 0, embW, nullptr);

    // CSR build (bucketed)
    bucket_count_kernel<<<256, 256, 0, stream>>>(dst, E, bucketCount);
    bucket_scan_kernel<<<1, 256, 0, stream>>>(bucketCount, bucketBase, bucketCursor);
    scatter_kernel<<<(E + K3E - 1) / K3E, 256, 0, stream>>>(src, dst, x, bucketCursor, ebuf, E);
    csr_kernel<<<NBUCK, 256, 0, stream>>>(ebuf, bucketBase, rowptr, col, N, E);

    // GCN gather
    gcn_kernel<<<2048, 256, (size_t)V * D * 4, stream>>>(rowptr, col, embW, h1, N, V);

    // SAGE: A = h1@Wl, B = h1@Wr (dual GEMM), then fused agg epilogue
    int gb = (N + 63) / 64;
    gemm64_kernel<<<gb, 256, 0, stream>>>(h1, N, Wsl, Wsr, nullptr, 0, A, B);
    sage_agg_kernel<<<(N + 3) / 4, 256, 0, stream>>>(rowptr, col, A, B, h2, N);

    // GIN: C = h2@W1, t = relu(C + agg(C) + b1), h3 = relu(t@W2 + b2)
    gemm64_kernel<<<gb, 256, 0, stream>>>(h2, N, Wg1, nullptr, nullptr, 0, C, nullptr);
    gin_agg_kernel<<<(N + 3) / 4, 256, 0, stream>>>(rowptr, col, C, bg1, t, N);
    gemm64_kernel<<<gb, 256, 0, stream>>>(t, N, Wg2, nullptr, bg2, 1, h3, nullptr);

    // pooling (16 waves/graph, LDS reduce)
    pool_final_kernel<<<G, 1024, 0, stream>>>(h1, h2, h3, batch, N, Wp1, Wp2, Wp3, out, G);
}

// Round 6
// 274.940 us; speedup vs baseline: 1.4444x; 1.1166x over previous
//
#include <hip/hip_runtime.h>
#include <hip/hip_bf16.h>
#include <hip/hip_fp16.h>

#define D 64
#define K3E 4096

// Edge word packing (requires N <= 65536, V <= 128 — true for this problem):
//   bits [0:15]  = src node
//   bits [16:22] = x[src]   (vocab id)
//   bits [23:30] = dst & 255 (node index within its 256-node bucket)

// ================= register-tiled fp32 GEMM: out = act(in[nrows x 64] @ W + bias) =================

__global__ __launch_bounds__(256) void gemm64_kernel(
    const float* __restrict__ in, int nrows,
    const float* __restrict__ W1, const float* __restrict__ W2,
    const float* __restrict__ bias, int do_relu,
    float* __restrict__ out1, float* __restrict__ out2)
{
    __shared__ float At[64][68];
    __shared__ float Ws1[64][64];
    __shared__ float Ws2[64][64];
    int tid = threadIdx.x;
    {
        const float4* w1v = (const float4*)W1;
        float4* s1 = (float4*)&Ws1[0][0];
        for (int i = tid; i < 1024; i += 256) s1[i] = w1v[i];
        if (W2) {
            const float4* w2v = (const float4*)W2;
            float4* s2 = (float4*)&Ws2[0][0];
            for (int i = tid; i < 1024; i += 256) s2[i] = w2v[i];
        }
    }
    int r0 = blockIdx.x * 64;
    for (int i = tid; i < 1024; i += 256) {
        int r = i >> 4, c4 = i & 15;
        int gr = r0 + r; if (gr >= nrows) gr = nrows - 1;
        float4 v = ((const float4*)(in + (size_t)gr * D))[c4];
        float* dp = &At[r][c4 * 4];
        dp[0] = v.x; dp[1] = v.y; dp[2] = v.z; dp[3] = v.w;
    }
    __syncthreads();

    int cg = tid & 15;
    int rg = tid >> 4;
    float acc1[4][4] = {{0.f}}, acc2[4][4] = {{0.f}};

    for (int k0 = 0; k0 < 64; k0 += 4) {
        float4 a[4], w1[4];
#pragma unroll
        for (int i = 0; i < 4; ++i) a[i] = *(const float4*)&At[4 * rg + i][k0];
#pragma unroll
        for (int j = 0; j < 4; ++j) w1[j] = *(const float4*)&Ws1[k0 + j][cg * 4];
#pragma unroll
        for (int i = 0; i < 4; ++i) {
            float av[4] = {a[i].x, a[i].y, a[i].z, a[i].w};
#pragma unroll
            for (int kk = 0; kk < 4; ++kk) {
                acc1[i][0] += av[kk] * w1[kk].x;
                acc1[i][1] += av[kk] * w1[kk].y;
                acc1[i][2] += av[kk] * w1[kk].z;
                acc1[i][3] += av[kk] * w1[kk].w;
            }
        }
        if (W2) {
            float4 w2[4];
#pragma unroll
            for (int j = 0; j < 4; ++j) w2[j] = *(const float4*)&Ws2[k0 + j][cg * 4];
#pragma unroll
            for (int i = 0; i < 4; ++i) {
                float av[4] = {a[i].x, a[i].y, a[i].z, a[i].w};
#pragma unroll
                for (int kk = 0; kk < 4; ++kk) {
                    acc2[i][0] += av[kk] * w2[kk].x;
                    acc2[i][1] += av[kk] * w2[kk].y;
                    acc2[i][2] += av[kk] * w2[kk].z;
                    acc2[i][3] += av[kk] * w2[kk].w;
                }
            }
        }
    }

    float4 bv = make_float4(0.f, 0.f, 0.f, 0.f);
    if (bias) bv = ((const float4*)bias)[cg];
#pragma unroll
    for (int i = 0; i < 4; ++i) {
        int gr = r0 + 4 * rg + i;
        if (gr < nrows) {
            float4 o;
            o.x = acc1[i][0] + bv.x; o.y = acc1[i][1] + bv.y;
            o.z = acc1[i][2] + bv.z; o.w = acc1[i][3] + bv.w;
            if (do_relu) {
                o.x = fmaxf(o.x, 0.f); o.y = fmaxf(o.y, 0.f);
                o.z = fmaxf(o.z, 0.f); o.w = fmaxf(o.w, 0.f);
            }
            ((float4*)(out1 + (size_t)gr * D))[cg] = o;
            if (out2) {
                float4 o2;
                o2.x = acc2[i][0]; o2.y = acc2[i][1]; o2.z = acc2[i][2]; o2.w = acc2[i][3];
                ((float4*)(out2 + (size_t)gr * D))[cg] = o2;
            }
        }
    }
}

// ===== GEMM variant: out1 is fp16 (gather-bound consumer), optional out2 fp32 =====

__global__ __launch_bounds__(256) void gemm64_h_kernel(
    const float* __restrict__ in, int nrows,
    const float* __restrict__ W1, const float* __restrict__ W2,
    __half* __restrict__ out1h, float* __restrict__ out2)
{
    __shared__ float At[64][68];
    __shared__ float Ws1[64][64];
    __shared__ float Ws2[64][64];
    int tid = threadIdx.x;
    {
        const float4* w1v = (const float4*)W1;
        float4* s1 = (float4*)&Ws1[0][0];
        for (int i = tid; i < 1024; i += 256) s1[i] = w1v[i];
        if (W2) {
            const float4* w2v = (const float4*)W2;
            float4* s2 = (float4*)&Ws2[0][0];
            for (int i = tid; i < 1024; i += 256) s2[i] = w2v[i];
        }
    }
    int r0 = blockIdx.x * 64;
    for (int i = tid; i < 1024; i += 256) {
        int r = i >> 4, c4 = i & 15;
        int gr = r0 + r; if (gr >= nrows) gr = nrows - 1;
        float4 v = ((const float4*)(in + (size_t)gr * D))[c4];
        float* dp = &At[r][c4 * 4];
        dp[0] = v.x; dp[1] = v.y; dp[2] = v.z; dp[3] = v.w;
    }
    __syncthreads();

    int cg = tid & 15;
    int rg = tid >> 4;
    float acc1[4][4] = {{0.f}}, acc2[4][4] = {{0.f}};

    for (int k0 = 0; k0 < 64; k0 += 4) {
        float4 a[4], w1[4];
#pragma unroll
        for (int i = 0; i < 4; ++i) a[i] = *(const float4*)&At[4 * rg + i][k0];
#pragma unroll
        for (int j = 0; j < 4; ++j) w1[j] = *(const float4*)&Ws1[k0 + j][cg * 4];
#pragma unroll
        for (int i = 0; i < 4; ++i) {
            float av[4] = {a[i].x, a[i].y, a[i].z, a[i].w};
#pragma unroll
            for (int kk = 0; kk < 4; ++kk) {
                acc1[i][0] += av[kk] * w1[kk].x;
                acc1[i][1] += av[kk] * w1[kk].y;
                acc1[i][2] += av[kk] * w1[kk].z;
                acc1[i][3] += av[kk] * w1[kk].w;
            }
        }
        if (W2) {
            float4 w2[4];
#pragma unroll
            for (int j = 0; j < 4; ++j) w2[j] = *(const float4*)&Ws2[k0 + j][cg * 4];
#pragma unroll
            for (int i = 0; i < 4; ++i) {
                float av[4] = {a[i].x, a[i].y, a[i].z, a[i].w};
#pragma unroll
                for (int kk = 0; kk < 4; ++kk) {
                    acc2[i][0] += av[kk] * w2[kk].x;
                    acc2[i][1] += av[kk] * w2[kk].y;
                    acc2[i][2] += av[kk] * w2[kk].z;
                    acc2[i][3] += av[kk] * w2[kk].w;
                }
            }
        }
    }

#pragma unroll
    for (int i = 0; i < 4; ++i) {
        int gr = r0 + 4 * rg + i;
        if (gr < nrows) {
            float2 oh;
            *(__half2*)&oh.x = __floats2half2_rn(acc1[i][0], acc1[i][1]);
            *(__half2*)&oh.y = __floats2half2_rn(acc1[i][2], acc1[i][3]);
            ((float2*)(out1h + (size_t)gr * D))[cg] = oh;
            if (out2) {
                float4 o2;
                o2.x = acc2[i][0]; o2.y = acc2[i][1]; o2.z = acc2[i][2]; o2.w = acc2[i][3];
                ((float4*)(out2 + (size_t)gr * D))[cg] = o2;
            }
        }
    }
}

// ================= bucketed CSR build =================

__global__ __launch_bounds__(256) void bucket_count_kernel(const int* __restrict__ dst, int E,
                                                           int* __restrict__ bucketCount) {
    __shared__ int hist[256];
    int t = threadIdx.x;
    hist[t] = 0;
    __syncthreads();
    for (int e = blockIdx.x * 256 + t; e < E; e += gridDim.x * 256)
        atomicAdd(&hist[dst[e] >> 8], 1);
    __syncthreads();
    int c = hist[t];
    if (c) atomicAdd(&bucketCount[t], c);
}

__global__ void bucket_scan_kernel(const int* __restrict__ bucketCount,
                                   int* __restrict__ bucketBase, int* __restrict__ bucketCursor) {
    __shared__ int lds[256];
    int t = threadIdx.x;
    int c = bucketCount[t];
    lds[t] = c;
    __syncthreads();
    for (int off = 1; off < 256; off <<= 1) {
        int v = (t >= off) ? lds[t - off] : 0;
        __syncthreads();
        lds[t] += v;
        __syncthreads();
    }
    int excl = lds[t] - c;
    bucketBase[t] = excl;
    bucketCursor[t] = excl;
    if (t == 255) bucketBase[256] = lds[t];
}

__global__ __launch_bounds__(256) void scatter_kernel(const int* __restrict__ src,
                                                      const int* __restrict__ dst,
                                                      const int* __restrict__ x,
                                                      int* __restrict__ bucketCursor,
                                                      int* __restrict__ ebuf, int E) {
    __shared__ int uu[K3E];
    __shared__ unsigned char bb[K3E];
    __shared__ int hist[256];
    __shared__ int resBase[256];
    int t = threadIdx.x;
    hist[t] = 0;
    __syncthreads();
    int e0 = blockIdx.x * K3E;
    int cnt = E - e0; if (cnt > K3E) cnt = K3E;
    for (int i = t; i < cnt; i += 256) {
        int e = e0 + i;
        int s = src[e];
        int d = dst[e];
        int xs = x[s];
        uu[i] = s | (xs << 16) | ((d & 255) << 23);
        int b = d >> 8;
        bb[i] = (unsigned char)b;
        atomicAdd(&hist[b], 1);
    }
    __syncthreads();
    int c = hist[t];
    if (c) resBase[t] = atomicAdd(&bucketCursor[t], c);
    __syncthreads();
    hist[t] = 0;
    __syncthreads();
    for (int i = t; i < cnt; i += 256) {
        int b = bb[i];
        int r = atomicAdd(&hist[b], 1);
        ebuf[resBase[b] + r] = uu[i];
    }
}

__global__ __launch_bounds__(256) void csr_kernel(const int* __restrict__ ebuf,
                                                  const int* __restrict__ bucketBase,
                                                  int* __restrict__ rowptr, int* __restrict__ col,
                                                  int N, int E) {
    __shared__ int hist[256];
    __shared__ int sc[256];
    int b = blockIdx.x, t = threadIdx.x;
    int base = bucketBase[b], endb = bucketBase[b + 1];
    int m = endb - base;
    hist[t] = 0;
    __syncthreads();
    for (int i = t; i < m; i += 256)
        atomicAdd(&hist[(ebuf[base + i] >> 23) & 255], 1);
    __syncthreads();
    int v = hist[t];
    sc[t] = v;
    __syncthreads();
    for (int off = 1; off < 256; off <<= 1) {
        int w = (t >= off) ? sc[t - off] : 0;
        __syncthreads();
        sc[t] += w;
        __syncthreads();
    }
    int excl = sc[t] - v;
    int node = (b << 8) + t;
    if (node < N) rowptr[node] = base + excl;
    if (b == gridDim.x - 1 && t == 0) rowptr[N] = E;
    __syncthreads();
    hist[t] = excl;   // running local cursor
    __syncthreads();
    for (int i = t; i < m; i += 256) {
        int u = ebuf[base + i];
        int dl = (u >> 23) & 255;
        int r = atomicAdd(&hist[dl], 1);
        col[base + r] = u;
    }
}

// ================= GCN: h1[v] = relu( sum embW[x[u]] ) — 2 edges per ds_read_b64 =================

__global__ __launch_bounds__(256) void gcn_kernel(const int* __restrict__ rowptr,
                                                  const int* __restrict__ col,
                                                  const float* __restrict__ embW,
                                                  float* __restrict__ h1, int N, int V) {
    extern __shared__ float lembW[];
    int tid = threadIdx.x;
    for (int i = tid; i < V * D; i += 256) lembW[i] = embW[i];
    __syncthreads();
    int lane = tid & 63;
    int g2 = lane >> 5, lj = lane & 31;   // group handles edge e+g2; lj covers 2 floats
    int wid = (blockIdx.x * 256 + tid) >> 6;
    int stride = (gridDim.x * 256) >> 6;
    for (int v = wid; v < N; v += stride) {
        int beg = rowptr[v], end = rowptr[v + 1];
        float ax = 0.f, ay = 0.f;
        int e0 = beg;
        for (; e0 + 8 <= end; e0 += 8) {
            int x0 = (col[e0 + 0 + g2] >> 16) & 0x7F;
            int x1 = (col[e0 + 2 + g2] >> 16) & 0x7F;
            int x2 = (col[e0 + 4 + g2] >> 16) & 0x7F;
            int x3 = (col[e0 + 6 + g2] >> 16) & 0x7F;
            float2 f0 = *((const float2*)(lembW + x0 * D) + lj);
            float2 f1 = *((const float2*)(lembW + x1 * D) + lj);
            float2 f2 = *((const float2*)(lembW + x2 * D) + lj);
            float2 f3 = *((const float2*)(lembW + x3 * D) + lj);
            ax += f0.x; ay += f0.y; ax += f1.x; ay += f1.y;
            ax += f2.x; ay += f2.y; ax += f3.x; ay += f3.y;
        }
        for (int e = e0 + g2; e < end; e += 2) {
            int xu = (col[e] >> 16) & 0x7F;
            float2 f = *((const float2*)(lembW + xu * D) + lj);
            ax += f.x; ay += f.y;
        }
        ax += __shfl_xor(ax, 32);
        ay += __shfl_xor(ay, 32);
        if (g2 == 0)
            ((float2*)(h1 + (size_t)v * D))[lj] = make_float2(fmaxf(ax, 0.f), fmaxf(ay, 0.f));
    }
}

// ================= SAGE epilogue: h2 = relu( agg(A)/deg + B ), A fp16 — 4 edges/instr =================

__global__ __launch_bounds__(256) void sage_agg_kernel(const int* __restrict__ rowptr,
                                                       const int* __restrict__ col,
                                                       const __half* __restrict__ A,
                                                       const float* __restrict__ B,
                                                       float* __restrict__ h2, int N) {
    int tid = threadIdx.x;
    int lane = tid & 63;
    int grp = lane >> 4, li = lane & 15;  // group handles edge e+grp; li covers 4 halves
    int v = blockIdx.x * 4 + (tid >> 6);
    if (v >= N) return;
    int beg = rowptr[v], end = rowptr[v + 1];
    float a0 = 0.f, a1 = 0.f, a2 = 0.f, a3 = 0.f;
    int e0 = beg;
    for (; e0 + 16 <= end; e0 += 16) {
#pragma unroll
        for (int j = 0; j < 4; ++j) {
            int u = col[e0 + 4 * j + grp] & 0xFFFF;
            float2 r = *((const float2*)(A + (size_t)u * D) + li);
            float2 f01 = __half22float2(*(const __half2*)&r.x);
            float2 f23 = __half22float2(*(const __half2*)&r.y);
            a0 += f01.x; a1 += f01.y; a2 += f23.x; a3 += f23.y;
        }
    }
    for (int e = e0 + grp; e < end; e += 4) {
        int u = col[e] & 0xFFFF;
        float2 r = *((const float2*)(A + (size_t)u * D) + li);
        float2 f01 = __half22float2(*(const __half2*)&r.x);
        float2 f23 = __half22float2(*(const __half2*)&r.y);
        a0 += f01.x; a1 += f01.y; a2 += f23.x; a3 += f23.y;
    }
    a0 += __shfl_xor(a0, 16); a0 += __shfl_xor(a0, 32);
    a1 += __shfl_xor(a1, 16); a1 += __shfl_xor(a1, 32);
    a2 += __shfl_xor(a2, 16); a2 += __shfl_xor(a2, 32);
    a3 += __shfl_xor(a3, 16); a3 += __shfl_xor(a3, 32);
    if (grp == 0) {
        float inv = 1.f / fmaxf((float)(end - beg), 1.f);
        float4 b = ((const float4*)(B + (size_t)v * D))[li];
        float4 o;
        o.x = fmaxf(a0 * inv + b.x, 0.f);
        o.y = fmaxf(a1 * inv + b.y, 0.f);
        o.z = fmaxf(a2 * inv + b.z, 0.f);
        o.w = fmaxf(a3 * inv + b.w, 0.f);
        ((float4*)(h2 + (size_t)v * D))[li] = o;
    }
}

// ================= GIN epilogue: t = relu( C + agg(C) + b1 ), C fp16 — 4 edges/instr =================

__global__ __launch_bounds__(256) void gin_agg_kernel(const int* __restrict__ rowptr,
                                                      const int* __restrict__ col,
                                                      const __half* __restrict__ C,
                                                      const float* __restrict__ b1,
                                                      float* __restrict__ t, int N) {
    int tid = threadIdx.x;
    int lane = tid & 63;
    int grp = lane >> 4, li = lane & 15;
    int v = blockIdx.x * 4 + (tid >> 6);
    if (v >= N) return;
    int beg = rowptr[v], end = rowptr[v + 1];
    float a0 = 0.f, a1 = 0.f, a2 = 0.f, a3 = 0.f;
    int e0 = beg;
    for (; e0 + 16 <= end; e0 += 16) {
#pragma unroll
        for (int j = 0; j < 4; ++j) {
            int u = col[e0 + 4 * j + grp] & 0xFFFF;
            float2 r = *((const float2*)(C + (size_t)u * D) + li);
            float2 f01 = __half22float2(*(const __half2*)&r.x);
            float2 f23 = __half22float2(*(const __half2*)&r.y);
            a0 += f01.x; a1 += f01.y; a2 += f23.x; a3 += f23.y;
        }
    }
    for (int e = e0 + grp; e < end; e += 4) {
        int u = col[e] & 0xFFFF;
        float2 r = *((const float2*)(C + (size_t)u * D) + li);
        float2 f01 = __half22float2(*(const __half2*)&r.x);
        float2 f23 = __half22float2(*(const __half2*)&r.y);
        a0 += f01.x; a1 += f01.y; a2 += f23.x; a3 += f23.y;
    }
    a0 += __shfl_xor(a0, 16); a0 += __shfl_xor(a0, 32);
    a1 += __shfl_xor(a1, 16); a1 += __shfl_xor(a1, 32);
    a2 += __shfl_xor(a2, 16); a2 += __shfl_xor(a2, 32);
    a3 += __shfl_xor(a3, 16); a3 += __shfl_xor(a3, 32);
    if (grp == 0) {
        float2 rs = *((const float2*)(C + (size_t)v * D) + li);   // self term
        float2 s01 = __half22float2(*(const __half2*)&rs.x);
        float2 s23 = __half22float2(*(const __half2*)&rs.y);
        float4 bb = ((const float4*)b1)[li];
        float4 o;
        o.x = fmaxf(s01.x + a0 + bb.x, 0.f);
        o.y = fmaxf(s01.y + a1 + bb.y, 0.f);
        o.z = fmaxf(s23.x + a2 + bb.z, 0.f);
        o.w = fmaxf(s23.y + a3 + bb.w, 0.f);
        ((float4*)(t + (size_t)v * D))[li] = o;
    }
}

// ================= pooling: 16 waves per graph + LDS tree reduce =================

__global__ __launch_bounds__(1024) void pool_final_kernel(
    const float* __restrict__ h1, const float* __restrict__ h2,
    const float* __restrict__ h3,
    const int* __restrict__ batch, int N,
    const float* __restrict__ W1, const float* __restrict__ W2,
    const float* __restrict__ W3, float* __restrict__ out, int G) {
    __shared__ float r1[16][64];
    __shared__ float r2[16][64];
    __shared__ float r3[16][64];
    int g = blockIdx.x;
    int tid = threadIdx.x;
    int w = tid >> 6, lane = tid & 63;

    int lo = 0, hi = N;
    while (lo < hi) { int mid = (lo + hi) >> 1; if (batch[mid] < g) lo = mid + 1; else hi = mid; }
    int beg = lo;
    hi = N;
    while (lo < hi) { int mid = (lo + hi) >> 1; if (batch[mid] < g + 1) lo = mid + 1; else hi = mid; }
    int end = lo;

    float s1 = 0.f, s2 = 0.f, s3 = 0.f;
    for (int v = beg + w; v < end; v += 16) {
        size_t idx = (size_t)v * D + lane;
        s1 += h1[idx];
        s2 += h2[idx];
        s3 += h3[idx];
    }
    r1[w][lane] = s1; r2[w][lane] = s2; r3[w][lane] = s3;
    __syncthreads();
#pragma unroll
    for (int stride = 8; stride >= 1; stride >>= 1) {
        if (w < stride) {
            r1[w][lane] += r1[w + stride][lane];
            r2[w][lane] += r2[w + stride][lane];
            r3[w][lane] += r3[w + stride][lane];
        }
        __syncthreads();
    }
    if (w == 0) {
        float inv = 1.f / fmaxf((float)(end - beg), 1.f);
        float p1 = r1[0][lane] * inv, p2 = r2[0][lane] * inv, p3 = r3[0][lane] * inv;
        float acc = 0.f;
#pragma unroll
        for (int k = 0; k < D; ++k) {
            acc += __shfl(p1, k) * W1[k * D + lane]
                 + __shfl(p2, k) * W2[k * D + lane]
                 + __shfl(p3, k) * W3[k * D + lane];
        }
        out[(size_t)g * D + lane] = fmaxf(acc, 0.f);
    }
}

// ================= launch =================

static inline size_t align256(size_t x) { return (x + 255) & ~(size_t)255; }

extern "C" void kernel_launch(void* const* d_in, const int* in_sizes, int n_in,
                              void* d_out, int out_size, void* d_ws, size_t ws_size,
                              hipStream_t stream) {
    const int* x      = (const int*)d_in[0];
    const int* ei     = (const int*)d_in[1];
    const int* batch  = (const int*)d_in[2];
    const float* emb  = (const float*)d_in[3];
    const float* Wgcn = (const float*)d_in[4];
    const float* Wsl  = (const float*)d_in[5];
    const float* Wsr  = (const float*)d_in[6];
    const float* Wg1  = (const float*)d_in[7];
    const float* bg1  = (const float*)d_in[8];
    const float* Wg2  = (const float*)d_in[9];
    const float* bg2  = (const float*)d_in[10];
    const float* Wp1  = (const float*)d_in[11];
    const float* Wp2  = (const float*)d_in[12];
    const float* Wp3  = (const float*)d_in[13];
    float* out = (float*)d_out;

    const int N = in_sizes[0];
    const int E = in_sizes[1] / 2;
    const int V = in_sizes[3] / D;
    const int G = out_size / D;
    const int* src = ei;
    const int* dst = ei + E;
    const int NBUCK = (N + 255) >> 8;

    // workspace layout
    char* base = (char*)d_ws;
    size_t off = 0;
    float* embW    = (float*)(base + off); off = align256(off + (size_t)V * D * 4);
    int* bucketCount  = (int*)(base + off); off = align256(off + 256 * 4);
    int* bucketBase   = (int*)(base + off); off = align256(off + 257 * 4);
    int* bucketCursor = (int*)(base + off); off = align256(off + 256 * 4);
    int* rowptr    = (int*)(base + off);   off = align256(off + (size_t)(N + 1) * 4);
    int* ebuf      = (int*)(base + off);   off = align256(off + (size_t)E * 4);
    int* col       = (int*)(base + off);   off = align256(off + (size_t)E * 4);
    float* h1      = (float*)(base + off); off = align256(off + (size_t)N * D * 4);
    float* h2      = (float*)(base + off); off = align256(off + (size_t)N * D * 4);
    float* h3      = (float*)(base + off); off = align256(off + (size_t)N * D * 4);
    __half* Ah     = (__half*)(base + off); off = align256(off + (size_t)N * D * 2);
    float* B       = (float*)(base + off); off = align256(off + (size_t)N * D * 4);
    (void)ws_size;

    __half* Ch = Ah;  // reuse: Ah dead after sage_agg
    float*  t  = B;   // reuse: B dead after sage_agg

    hipMemsetAsync(bucketCount, 0, 256 * 4, stream);

    // embW = emb @ Wgcn
    gemm64_kernel<<<(V + 63) / 64, 256, 0, stream>>>(emb, V, Wgcn, nullptr, nullptr, 0, embW, nullptr);

    // CSR build (bucketed)
    bucket_count_kernel<<<256, 256, 0, stream>>>(dst, E, bucketCount);
    bucket_scan_kernel<<<1, 256, 0, stream>>>(bucketCount, bucketBase, bucketCursor);
    scatter_kernel<<<(E + K3E - 1) / K3E, 256, 0, stream>>>(src, dst, x, bucketCursor, ebuf, E);
    csr_kernel<<<NBUCK, 256, 0, stream>>>(ebuf, bucketBase, rowptr, col, N, E);

    // GCN gather
    gcn_kernel<<<2048, 256, (size_t)V * D * 4, stream>>>(rowptr, col, embW, h1, N, V);

    // SAGE: Ah = fp16(h1@Wl), B = h1@Wr (dual GEMM), then fused agg epilogue
    int gb = (N + 63) / 64;
    gemm64_h_kernel<<<gb, 256, 0, stream>>>(h1, N, Wsl, Wsr, Ah, B);
    sage_agg_kernel<<<(N + 3) / 4, 256, 0, stream>>>(rowptr, col, Ah, B, h2, N);

    // GIN: Ch = fp16(h2@W1), t = relu(C + agg(C) + b1), h3 = relu(t@W2 + b2)
    gemm64_h_kernel<<<gb, 256, 0, stream>>>(h2, N, Wg1, nullptr, Ch, nullptr);
    gin_agg_kernel<<<(N + 3) / 4, 256, 0, stream>>>(rowptr, col, Ch, bg1, t, N);
    gemm64_kernel<<<gb, 256, 0, stream>>>(t, N, Wg2, nullptr, bg2, 1, h3, nullptr);

    // pooling (16 waves/graph, LDS reduce)
    pool_final_kernel<<<G, 1024, 0, stream>>>(h1, h2, h3, batch, N, Wp1, Wp2, Wp3, out, G);
}

// Round 7
// 269.459 us; speedup vs baseline: 1.4738x; 1.0203x over previous
//
#include <hip/hip_runtime.h>
#include <hip/hip_bf16.h>
#include <hip/hip_fp16.h>

#define D 64
#define K3E 4096

// Edge word packing (requires N <= 65536, V <= 128 — true for this problem):
//   bits [0:15]  = src node
//   bits [16:22] = x[src]   (vocab id)
//   bits [23:30] = dst & 255 (node index within its 256-node bucket)

// ================= fp32 GEMM (used once for embW, V=128 rows) =================

__global__ __launch_bounds__(256) void gemm64_kernel(
    const float* __restrict__ in, int nrows,
    const float* __restrict__ W1,
    float* __restrict__ out1)
{
    __shared__ float At[64][68];
    __shared__ float Ws1[64][64];
    int tid = threadIdx.x;
    {
        const float4* w1v = (const float4*)W1;
        float4* s1 = (float4*)&Ws1[0][0];
        for (int i = tid; i < 1024; i += 256) s1[i] = w1v[i];
    }
    int r0 = blockIdx.x * 64;
    for (int i = tid; i < 1024; i += 256) {
        int r = i >> 4, c4 = i & 15;
        int gr = r0 + r; if (gr >= nrows) gr = nrows - 1;
        float4 v = ((const float4*)(in + (size_t)gr * D))[c4];
        float* dp = &At[r][c4 * 4];
        dp[0] = v.x; dp[1] = v.y; dp[2] = v.z; dp[3] = v.w;
    }
    __syncthreads();

    int cg = tid & 15;
    int rg = tid >> 4;
    float acc1[4][4] = {{0.f}};

    for (int k0 = 0; k0 < 64; k0 += 4) {
        float4 a[4], w1[4];
#pragma unroll
        for (int i = 0; i < 4; ++i) a[i] = *(const float4*)&At[4 * rg + i][k0];
#pragma unroll
        for (int j = 0; j < 4; ++j) w1[j] = *(const float4*)&Ws1[k0 + j][cg * 4];
#pragma unroll
        for (int i = 0; i < 4; ++i) {
            float av[4] = {a[i].x, a[i].y, a[i].z, a[i].w};
#pragma unroll
            for (int kk = 0; kk < 4; ++kk) {
                acc1[i][0] += av[kk] * w1[kk].x;
                acc1[i][1] += av[kk] * w1[kk].y;
                acc1[i][2] += av[kk] * w1[kk].z;
                acc1[i][3] += av[kk] * w1[kk].w;
            }
        }
    }
#pragma unroll
    for (int i = 0; i < 4; ++i) {
        int gr = r0 + 4 * rg + i;
        if (gr < nrows) {
            float4 o;
            o.x = acc1[i][0]; o.y = acc1[i][1]; o.z = acc1[i][2]; o.w = acc1[i][3];
            ((float4*)(out1 + (size_t)gr * D))[cg] = o;
        }
    }
}

// ===== fp16-in / fp16-out GEMM (fp32 LDS + fp32 accumulate), optional dual output =====

__global__ __launch_bounds__(256) void gemm64h_kernel(
    const __half* __restrict__ in, int nrows,
    const float* __restrict__ W1, const float* __restrict__ W2,
    const float* __restrict__ bias, int do_relu,
    __half* __restrict__ out1, __half* __restrict__ out2)
{
    __shared__ float At[64][68];
    __shared__ float Ws1[64][64];
    __shared__ float Ws2[64][64];
    int tid = threadIdx.x;
    {
        const float4* w1v = (const float4*)W1;
        float4* s1 = (float4*)&Ws1[0][0];
        for (int i = tid; i < 1024; i += 256) s1[i] = w1v[i];
        if (W2) {
            const float4* w2v = (const float4*)W2;
            float4* s2 = (float4*)&Ws2[0][0];
            for (int i = tid; i < 1024; i += 256) s2[i] = w2v[i];
        }
    }
    int r0 = blockIdx.x * 64;
    // stage fp16 input rows -> fp32 LDS  (64 rows x 64 cols = 512 x float4-of-half8)
    for (int i = tid; i < 512; i += 256) {
        int r = i >> 3, c8 = i & 7;
        int gr = r0 + r; if (gr >= nrows) gr = nrows - 1;
        float4 hv = ((const float4*)(in + (size_t)gr * D))[c8];
        const __half2* hp = (const __half2*)&hv;
        float* dp = &At[r][c8 * 8];
        float2 f;
        f = __half22float2(hp[0]); dp[0] = f.x; dp[1] = f.y;
        f = __half22float2(hp[1]); dp[2] = f.x; dp[3] = f.y;
        f = __half22float2(hp[2]); dp[4] = f.x; dp[5] = f.y;
        f = __half22float2(hp[3]); dp[6] = f.x; dp[7] = f.y;
    }
    __syncthreads();

    int cg = tid & 15;
    int rg = tid >> 4;
    float acc1[4][4] = {{0.f}}, acc2[4][4] = {{0.f}};

    for (int k0 = 0; k0 < 64; k0 += 4) {
        float4 a[4], w1[4];
#pragma unroll
        for (int i = 0; i < 4; ++i) a[i] = *(const float4*)&At[4 * rg + i][k0];
#pragma unroll
        for (int j = 0; j < 4; ++j) w1[j] = *(const float4*)&Ws1[k0 + j][cg * 4];
#pragma unroll
        for (int i = 0; i < 4; ++i) {
            float av[4] = {a[i].x, a[i].y, a[i].z, a[i].w};
#pragma unroll
            for (int kk = 0; kk < 4; ++kk) {
                acc1[i][0] += av[kk] * w1[kk].x;
                acc1[i][1] += av[kk] * w1[kk].y;
                acc1[i][2] += av[kk] * w1[kk].z;
                acc1[i][3] += av[kk] * w1[kk].w;
            }
        }
        if (W2) {
            float4 w2[4];
#pragma unroll
            for (int j = 0; j < 4; ++j) w2[j] = *(const float4*)&Ws2[k0 + j][cg * 4];
#pragma unroll
            for (int i = 0; i < 4; ++i) {
                float av[4] = {a[i].x, a[i].y, a[i].z, a[i].w};
#pragma unroll
                for (int kk = 0; kk < 4; ++kk) {
                    acc2[i][0] += av[kk] * w2[kk].x;
                    acc2[i][1] += av[kk] * w2[kk].y;
                    acc2[i][2] += av[kk] * w2[kk].z;
                    acc2[i][3] += av[kk] * w2[kk].w;
                }
            }
        }
    }

    float4 bv = make_float4(0.f, 0.f, 0.f, 0.f);
    if (bias) bv = ((const float4*)bias)[cg];
#pragma unroll
    for (int i = 0; i < 4; ++i) {
        int gr = r0 + 4 * rg + i;
        if (gr < nrows) {
            float ox = acc1[i][0] + bv.x, oy = acc1[i][1] + bv.y;
            float oz = acc1[i][2] + bv.z, ow = acc1[i][3] + bv.w;
            if (do_relu) {
                ox = fmaxf(ox, 0.f); oy = fmaxf(oy, 0.f);
                oz = fmaxf(oz, 0.f); ow = fmaxf(ow, 0.f);
            }
            float2 oh;
            *(__half2*)&oh.x = __floats2half2_rn(ox, oy);
            *(__half2*)&oh.y = __floats2half2_rn(oz, ow);
            ((float2*)(out1 + (size_t)gr * D))[cg] = oh;
            if (out2) {
                float2 o2;
                *(__half2*)&o2.x = __floats2half2_rn(acc2[i][0], acc2[i][1]);
                *(__half2*)&o2.y = __floats2half2_rn(acc2[i][2], acc2[i][3]);
                ((float2*)(out2 + (size_t)gr * D))[cg] = o2;
            }
        }
    }
}

// ================= bucketed CSR build =================

__global__ __launch_bounds__(256) void bucket_count_kernel(const int* __restrict__ dst, int E,
                                                           int* __restrict__ bucketCount) {
    __shared__ int hist[256];
    int t = threadIdx.x;
    hist[t] = 0;
    __syncthreads();
    for (int e = blockIdx.x * 256 + t; e < E; e += gridDim.x * 256)
        atomicAdd(&hist[dst[e] >> 8], 1);
    __syncthreads();
    int c = hist[t];
    if (c) atomicAdd(&bucketCount[t], c);
}

__global__ void bucket_scan_kernel(const int* __restrict__ bucketCount,
                                   int* __restrict__ bucketBase, int* __restrict__ bucketCursor) {
    __shared__ int lds[256];
    int t = threadIdx.x;
    int c = bucketCount[t];
    lds[t] = c;
    __syncthreads();
    for (int off = 1; off < 256; off <<= 1) {
        int v = (t >= off) ? lds[t - off] : 0;
        __syncthreads();
        lds[t] += v;
        __syncthreads();
    }
    int excl = lds[t] - c;
    bucketBase[t] = excl;
    bucketCursor[t] = excl;
    if (t == 255) bucketBase[256] = lds[t];
}

__global__ __launch_bounds__(256) void scatter_kernel(const int* __restrict__ src,
                                                      const int* __restrict__ dst,
                                                      const int* __restrict__ x,
                                                      int* __restrict__ bucketCursor,
                                                      int* __restrict__ ebuf, int E) {
    __shared__ int uu[K3E];
    __shared__ unsigned char bb[K3E];
    __shared__ int hist[256];
    __shared__ int resBase[256];
    int t = threadIdx.x;
    hist[t] = 0;
    __syncthreads();
    int e0 = blockIdx.x * K3E;
    int cnt = E - e0; if (cnt > K3E) cnt = K3E;
    for (int i = t; i < cnt; i += 256) {
        int e = e0 + i;
        int s = src[e];
        int d = dst[e];
        int xs = x[s];
        uu[i] = s | (xs << 16) | ((d & 255) << 23);
        int b = d >> 8;
        bb[i] = (unsigned char)b;
        atomicAdd(&hist[b], 1);
    }
    __syncthreads();
    int c = hist[t];
    if (c) resBase[t] = atomicAdd(&bucketCursor[t], c);
    __syncthreads();
    hist[t] = 0;
    __syncthreads();
    for (int i = t; i < cnt; i += 256) {
        int b = bb[i];
        int r = atomicAdd(&hist[b], 1);
        ebuf[resBase[b] + r] = uu[i];
    }
}

__global__ __launch_bounds__(256) void csr_kernel(const int* __restrict__ ebuf,
                                                  const int* __restrict__ bucketBase,
                                                  int* __restrict__ rowptr, int* __restrict__ col,
                                                  int N, int E) {
    __shared__ int hist[256];
    __shared__ int sc[256];
    int b = blockIdx.x, t = threadIdx.x;
    int base = bucketBase[b], endb = bucketBase[b + 1];
    int m = endb - base;
    hist[t] = 0;
    __syncthreads();
    for (int i = t; i < m; i += 256)
        atomicAdd(&hist[(ebuf[base + i] >> 23) & 255], 1);
    __syncthreads();
    int v = hist[t];
    sc[t] = v;
    __syncthreads();
    for (int off = 1; off < 256; off <<= 1) {
        int w = (t >= off) ? sc[t - off] : 0;
        __syncthreads();
        sc[t] += w;
        __syncthreads();
    }
    int excl = sc[t] - v;
    int node = (b << 8) + t;
    if (node < N) rowptr[node] = base + excl;
    if (b == gridDim.x - 1 && t == 0) rowptr[N] = E;
    __syncthreads();
    hist[t] = excl;   // running local cursor
    __syncthreads();
    for (int i = t; i < m; i += 256) {
        int u = ebuf[base + i];
        int dl = (u >> 23) & 255;
        int r = atomicAdd(&hist[dl], 1);
        col[base + r] = u;
    }
}

// ================= GCN: h1[v] = relu( sum embW[x[u]] ), h1 fp16 =================

__global__ __launch_bounds__(256) void gcn_kernel(const int* __restrict__ rowptr,
                                                  const int* __restrict__ col,
                                                  const float* __restrict__ embW,
                                                  __half* __restrict__ h1, int N, int V) {
    extern __shared__ float lembW[];
    int tid = threadIdx.x;
    for (int i = tid; i < V * D; i += 256) lembW[i] = embW[i];
    __syncthreads();
    int lane = tid & 63;
    int g2 = lane >> 5, lj = lane & 31;   // group handles edge e+g2; lj covers 2 floats
    int wid = (blockIdx.x * 256 + tid) >> 6;
    int stride = (gridDim.x * 256) >> 6;
    for (int v = wid; v < N; v += stride) {
        int beg = rowptr[v], end = rowptr[v + 1];
        float ax = 0.f, ay = 0.f;
        int e0 = beg;
        for (; e0 + 8 <= end; e0 += 8) {
            int x0 = (col[e0 + 0 + g2] >> 16) & 0x7F;
            int x1 = (col[e0 + 2 + g2] >> 16) & 0x7F;
            int x2 = (col[e0 + 4 + g2] >> 16) & 0x7F;
            int x3 = (col[e0 + 6 + g2] >> 16) & 0x7F;
            float2 f0 = *((const float2*)(lembW + x0 * D) + lj);
            float2 f1 = *((const float2*)(lembW + x1 * D) + lj);
            float2 f2 = *((const float2*)(lembW + x2 * D) + lj);
            float2 f3 = *((const float2*)(lembW + x3 * D) + lj);
            ax += f0.x; ay += f0.y; ax += f1.x; ay += f1.y;
            ax += f2.x; ay += f2.y; ax += f3.x; ay += f3.y;
        }
        for (int e = e0 + g2; e < end; e += 2) {
            int xu = (col[e] >> 16) & 0x7F;
            float2 f = *((const float2*)(lembW + xu * D) + lj);
            ax += f.x; ay += f.y;
        }
        ax += __shfl_xor(ax, 32);
        ay += __shfl_xor(ay, 32);
        if (g2 == 0)
            ((__half2*)(h1 + (size_t)v * D))[lj] =
                __floats2half2_rn(fmaxf(ax, 0.f), fmaxf(ay, 0.f));
    }
}

// ================= SAGE epilogue: h2 = relu( agg(A)/deg + B ), all fp16 =================

__global__ __launch_bounds__(256) void sage_agg_kernel(const int* __restrict__ rowptr,
                                                       const int* __restrict__ col,
                                                       const __half* __restrict__ A,
                                                       const __half* __restrict__ B,
                                                       __half* __restrict__ h2, int N) {
    int tid = threadIdx.x;
    int lane = tid & 63;
    int grp = lane >> 4, li = lane & 15;  // group handles edge e+grp; li covers 4 halves
    int v = blockIdx.x * 4 + (tid >> 6);
    if (v >= N) return;
    int beg = rowptr[v], end = rowptr[v + 1];
    float a0 = 0.f, a1 = 0.f, a2 = 0.f, a3 = 0.f;
    int e0 = beg;
    for (; e0 + 16 <= end; e0 += 16) {
#pragma unroll
        for (int j = 0; j < 4; ++j) {
            int u = col[e0 + 4 * j + grp] & 0xFFFF;
            float2 r = *((const float2*)(A + (size_t)u * D) + li);
            float2 f01 = __half22float2(*(const __half2*)&r.x);
            float2 f23 = __half22float2(*(const __half2*)&r.y);
            a0 += f01.x; a1 += f01.y; a2 += f23.x; a3 += f23.y;
        }
    }
    for (int e = e0 + grp; e < end; e += 4) {
        int u = col[e] & 0xFFFF;
        float2 r = *((const float2*)(A + (size_t)u * D) + li);
        float2 f01 = __half22float2(*(const __half2*)&r.x);
        float2 f23 = __half22float2(*(const __half2*)&r.y);
        a0 += f01.x; a1 += f01.y; a2 += f23.x; a3 += f23.y;
    }
    a0 += __shfl_xor(a0, 16); a0 += __shfl_xor(a0, 32);
    a1 += __shfl_xor(a1, 16); a1 += __shfl_xor(a1, 32);
    a2 += __shfl_xor(a2, 16); a2 += __shfl_xor(a2, 32);
    a3 += __shfl_xor(a3, 16); a3 += __shfl_xor(a3, 32);
    if (grp == 0) {
        float inv = 1.f / fmaxf((float)(end - beg), 1.f);
        float2 br = *((const float2*)(B + (size_t)v * D) + li);
        float2 b01 = __half22float2(*(const __half2*)&br.x);
        float2 b23 = __half22float2(*(const __half2*)&br.y);
        float2 oh;
        *(__half2*)&oh.x = __floats2half2_rn(fmaxf(a0 * inv + b01.x, 0.f),
                                             fmaxf(a1 * inv + b01.y, 0.f));
        *(__half2*)&oh.y = __floats2half2_rn(fmaxf(a2 * inv + b23.x, 0.f),
                                             fmaxf(a3 * inv + b23.y, 0.f));
        ((float2*)(h2 + (size_t)v * D))[li] = oh;
    }
}

// ================= GIN epilogue: t = relu( C + agg(C) + b1 ), fp16 =================

__global__ __launch_bounds__(256) void gin_agg_kernel(const int* __restrict__ rowptr,
                                                      const int* __restrict__ col,
                                                      const __half* __restrict__ C,
                                                      const float* __restrict__ b1,
                                                      __half* __restrict__ t, int N) {
    int tid = threadIdx.x;
    int lane = tid & 63;
    int grp = lane >> 4, li = lane & 15;
    int v = blockIdx.x * 4 + (tid >> 6);
    if (v >= N) return;
    int beg = rowptr[v], end = rowptr[v + 1];
    float a0 = 0.f, a1 = 0.f, a2 = 0.f, a3 = 0.f;
    int e0 = beg;
    for (; e0 + 16 <= end; e0 += 16) {
#pragma unroll
        for (int j = 0; j < 4; ++j) {
            int u = col[e0 + 4 * j + grp] & 0xFFFF;
            float2 r = *((const float2*)(C + (size_t)u * D) + li);
            float2 f01 = __half22float2(*(const __half2*)&r.x);
            float2 f23 = __half22float2(*(const __half2*)&r.y);
            a0 += f01.x; a1 += f01.y; a2 += f23.x; a3 += f23.y;
        }
    }
    for (int e = e0 + grp; e < end; e += 4) {
        int u = col[e] & 0xFFFF;
        float2 r = *((const float2*)(C + (size_t)u * D) + li);
        float2 f01 = __half22float2(*(const __half2*)&r.x);
        float2 f23 = __half22float2(*(const __half2*)&r.y);
        a0 += f01.x; a1 += f01.y; a2 += f23.x; a3 += f23.y;
    }
    a0 += __shfl_xor(a0, 16); a0 += __shfl_xor(a0, 32);
    a1 += __shfl_xor(a1, 16); a1 += __shfl_xor(a1, 32);
    a2 += __shfl_xor(a2, 16); a2 += __shfl_xor(a2, 32);
    a3 += __shfl_xor(a3, 16); a3 += __shfl_xor(a3, 32);
    if (grp == 0) {
        float2 rs = *((const float2*)(C + (size_t)v * D) + li);   // self term
        float2 s01 = __half22float2(*(const __half2*)&rs.x);
        float2 s23 = __half22float2(*(const __half2*)&rs.y);
        float4 bb = ((const float4*)b1)[li];
        float2 oh;
        *(__half2*)&oh.x = __floats2half2_rn(fmaxf(s01.x + a0 + bb.x, 0.f),
                                             fmaxf(s01.y + a1 + bb.y, 0.f));
        *(__half2*)&oh.y = __floats2half2_rn(fmaxf(s23.x + a2 + bb.z, 0.f),
                                             fmaxf(s23.y + a3 + bb.w, 0.f));
        ((float2*)(t + (size_t)v * D))[li] = oh;
    }
}

// ================= pooling: 16 waves per graph + LDS tree reduce (fp16 inputs) =================

__global__ __launch_bounds__(1024) void pool_final_kernel(
    const __half* __restrict__ h1, const __half* __restrict__ h2,
    const __half* __restrict__ h3,
    const int* __restrict__ batch, int N,
    const float* __restrict__ W1, const float* __restrict__ W2,
    const float* __restrict__ W3, float* __restrict__ out, int G) {
    __shared__ float r1[16][64];
    __shared__ float r2[16][64];
    __shared__ float r3[16][64];
    int g = blockIdx.x;
    int tid = threadIdx.x;
    int w = tid >> 6, lane = tid & 63;

    int lo = 0, hi = N;
    while (lo < hi) { int mid = (lo + hi) >> 1; if (batch[mid] < g) lo = mid + 1; else hi = mid; }
    int beg = lo;
    hi = N;
    while (lo < hi) { int mid = (lo + hi) >> 1; if (batch[mid] < g + 1) lo = mid + 1; else hi = mid; }
    int end = lo;

    float s1 = 0.f, s2 = 0.f, s3 = 0.f;
    for (int v = beg + w; v < end; v += 16) {
        size_t idx = (size_t)v * D + lane;
        s1 += __half2float(h1[idx]);
        s2 += __half2float(h2[idx]);
        s3 += __half2float(h3[idx]);
    }
    r1[w][lane] = s1; r2[w][lane] = s2; r3[w][lane] = s3;
    __syncthreads();
#pragma unroll
    for (int stride = 8; stride >= 1; stride >>= 1) {
        if (w < stride) {
            r1[w][lane] += r1[w + stride][lane];
            r2[w][lane] += r2[w + stride][lane];
            r3[w][lane] += r3[w + stride][lane];
        }
        __syncthreads();
    }
    if (w == 0) {
        float inv = 1.f / fmaxf((float)(end - beg), 1.f);
        float p1 = r1[0][lane] * inv, p2 = r2[0][lane] * inv, p3 = r3[0][lane] * inv;
        float acc = 0.f;
#pragma unroll
        for (int k = 0; k < D; ++k) {
            acc += __shfl(p1, k) * W1[k * D + lane]
                 + __shfl(p2, k) * W2[k * D + lane]
                 + __shfl(p3, k) * W3[k * D + lane];
        }
        out[(size_t)g * D + lane] = fmaxf(acc, 0.f);
    }
}

// ================= launch =================

static inline size_t align256(size_t x) { return (x + 255) & ~(size_t)255; }

extern "C" void kernel_launch(void* const* d_in, const int* in_sizes, int n_in,
                              void* d_out, int out_size, void* d_ws, size_t ws_size,
                              hipStream_t stream) {
    const int* x      = (const int*)d_in[0];
    const int* ei     = (const int*)d_in[1];
    const int* batch  = (const int*)d_in[2];
    const float* emb  = (const float*)d_in[3];
    const float* Wgcn = (const float*)d_in[4];
    const float* Wsl  = (const float*)d_in[5];
    const float* Wsr  = (const float*)d_in[6];
    const float* Wg1  = (const float*)d_in[7];
    const float* bg1  = (const float*)d_in[8];
    const float* Wg2  = (const float*)d_in[9];
    const float* bg2  = (const float*)d_in[10];
    const float* Wp1  = (const float*)d_in[11];
    const float* Wp2  = (const float*)d_in[12];
    const float* Wp3  = (const float*)d_in[13];
    float* out = (float*)d_out;

    const int N = in_sizes[0];
    const int E = in_sizes[1] / 2;
    const int V = in_sizes[3] / D;
    const int G = out_size / D;
    const int* src = ei;
    const int* dst = ei + E;
    const int NBUCK = (N + 255) >> 8;

    // workspace layout
    char* base = (char*)d_ws;
    size_t off = 0;
    float* embW    = (float*)(base + off); off = align256(off + (size_t)V * D * 4);
    int* bucketCount  = (int*)(base + off); off = align256(off + 256 * 4);
    int* bucketBase   = (int*)(base + off); off = align256(off + 257 * 4);
    int* bucketCursor = (int*)(base + off); off = align256(off + 256 * 4);
    int* rowptr    = (int*)(base + off);   off = align256(off + (size_t)(N + 1) * 4);
    int* ebuf      = (int*)(base + off);   off = align256(off + (size_t)E * 4);
    int* col       = (int*)(base + off);   off = align256(off + (size_t)E * 4);
    __half* h1     = (__half*)(base + off); off = align256(off + (size_t)N * D * 2);
    __half* h2     = (__half*)(base + off); off = align256(off + (size_t)N * D * 2);
    __half* h3     = (__half*)(base + off); off = align256(off + (size_t)N * D * 2);
    __half* Ah     = (__half*)(base + off); off = align256(off + (size_t)N * D * 2);
    __half* B      = (__half*)(base + off); off = align256(off + (size_t)N * D * 2);
    (void)ws_size;

    __half* Ch = Ah;  // reuse: Ah dead after sage_agg
    __half* t  = B;   // reuse: B dead after sage_agg

    hipMemsetAsync(bucketCount, 0, 256 * 4, stream);

    // embW = emb @ Wgcn (fp32, tiny)
    gemm64_kernel<<<(V + 63) / 64, 256, 0, stream>>>(emb, V, Wgcn, embW);

    // CSR build (bucketed)
    bucket_count_kernel<<<256, 256, 0, stream>>>(dst, E, bucketCount);
    bucket_scan_kernel<<<1, 256, 0, stream>>>(bucketCount, bucketBase, bucketCursor);
    scatter_kernel<<<(E + K3E - 1) / K3E, 256, 0, stream>>>(src, dst, x, bucketCursor, ebuf, E);
    csr_kernel<<<NBUCK, 256, 0, stream>>>(ebuf, bucketBase, rowptr, col, N, E);

    // GCN gather -> h1 (fp16)
    gcn_kernel<<<1024, 256, (size_t)V * D * 4, stream>>>(rowptr, col, embW, h1, N, V);

    // SAGE: Ah = fp16(h1@Wl), B = fp16(h1@Wr), then fused agg epilogue -> h2 (fp16)
    int gb = (N + 63) / 64;
    gemm64h_kernel<<<gb, 256, 0, stream>>>(h1, N, Wsl, Wsr, nullptr, 0, Ah, B);
    sage_agg_kernel<<<(N + 3) / 4, 256, 0, stream>>>(rowptr, col, Ah, B, h2, N);

    // GIN: Ch = fp16(h2@W1), t = relu(C + agg(C) + b1), h3 = fp16(relu(t@W2 + b2))
    gemm64h_kernel<<<gb, 256, 0, stream>>>(h2, N, Wg1, nullptr, nullptr, 0, Ch, nullptr);
    gin_agg_kernel<<<(N + 3) / 4, 256, 0, stream>>>(rowptr, col, Ch, bg1, t, N);
    gemm64h_kernel<<<gb, 256, 0, stream>>>(t, N, Wg2, nullptr, bg2, 1, h3, nullptr);

    // pooling (16 waves/graph, LDS reduce)
    pool_final_kernel<<<G, 1024, 0, stream>>>(h1, h2, h3, batch, N, Wp1, Wp2, Wp3, out, G);
}